// Round 4
// baseline (564.273 us; speedup 1.0000x reference)
//
#include <hip/hip_runtime.h>
#include <hip/hip_bf16.h>
#include <math.h>

#define B 128
#define V 32
#define H 128
#define LDA 296    // padded A row pitch in bf16 elems (592 B)
#define LDXC 40    // child-x row pitch in bf16 elems (80 B, 16B-aligned)
#define NBLK 256
#define NTHR 512

typedef __attribute__((ext_vector_type(8))) short bf16x8;
typedef __attribute__((ext_vector_type(4))) float f32x4;

__device__ inline f32x4 mfma_bf16(bf16x8 a, bf16x8 b, f32x4 c) {
    return __builtin_amdgcn_mfma_f32_16x16x32_bf16(a, b, c, 0, 0, 0);
}
__device__ inline unsigned short f2bf(float f) {
    __hip_bfloat16 h = __float2bfloat16(f);
    return __builtin_bit_cast(unsigned short, h);
}
__device__ inline float bf2f(unsigned short u) {
    unsigned int x = ((unsigned int)u) << 16;
    return __builtin_bit_cast(float, x);
}
__device__ inline float fast_sigmoid(float x) {
    float e = __builtin_amdgcn_exp2f(x * -1.44269504f);
    return __builtin_amdgcn_rcpf(1.f + e);
}
__device__ inline float fast_tanh(float x) {
    float e = __builtin_amdgcn_exp2f(x * 2.88539008f);   // exp(2x)
    return 1.f - 2.f * __builtin_amdgcn_rcpf(e + 1.f);
}

// ---------------------------------------------------------------------------
// Pack weights into MFMA B-fragment order + combined biases; zero the barrier.
// frag index = (ks*24 + g*8 + t)*64 + lane. Same (lane,elem)->k map as A-frags.
// ---------------------------------------------------------------------------
__global__ void prep_pack(const float* __restrict__ wir_w, const float* __restrict__ whr_w,
                          const float* __restrict__ wiz_w, const float* __restrict__ whz_w,
                          const float* __restrict__ win_w, const float* __restrict__ whn_w,
                          const float* __restrict__ wir_b, const float* __restrict__ whr_b,
                          const float* __restrict__ wiz_b, const float* __restrict__ whz_b,
                          const float* __restrict__ win_b, const float* __restrict__ whn_b,
                          unsigned short* __restrict__ wFrag, float* __restrict__ bias,
                          unsigned* __restrict__ bar)
{
    int idx = blockIdx.x * blockDim.x + threadIdx.x;
    if (idx == 0) *bar = 0u;
    if (idx < 9 * 24 * 64) {
        int lane = idx & 63;
        int ctks = idx >> 6;
        int ct = ctks % 24;
        int ks = ctks / 24;
        int g = ct >> 3;
        int t = ct & 7;
        int u = t * 16 + (lane & 15);
        const float* wi = (g == 0) ? wir_w : (g == 1) ? wiz_w : win_w;
        const float* wh = (g == 0) ? whr_w : (g == 1) ? whz_w : whn_w;
        unsigned short v[8] __attribute__((aligned(16)));
        #pragma unroll
        for (int i = 0; i < 8; ++i) {
            float f;
            if (ks == 0) { int k = 8 * (lane >> 4) + i; f = wi[u * V + k]; }
            else         { int k = (ks - 1) * 32 + 8 * (lane >> 4) + i; f = wh[u * 256 + k]; }
            v[i] = f2bf(f);
        }
        *(int4*)(wFrag + (size_t)idx * 8) = *(const int4*)v;
    }
    if (idx < 4 * H) {
        int s = idx / H, u = idx % H;
        float val;
        if (s == 0)      val = wir_b[u] + whr_b[u];
        else if (s == 1) val = wiz_b[u] + whz_b[u];
        else if (s == 2) val = win_b[u];
        else             val = whn_b[u];
        bias[idx] = val;
    }
}

// ---------------------------------------------------------------------------
// Device-scope grid barrier (monotonic counter; co-resident grid of NBLK).
// ---------------------------------------------------------------------------
__device__ inline void grid_barrier(unsigned* bar, unsigned expected) {
    __syncthreads();
    if (threadIdx.x == 0) {
        __threadfence();  // release our writes device-wide
        __hip_atomic_fetch_add(bar, 1u, __ATOMIC_ACQ_REL, __HIP_MEMORY_SCOPE_AGENT);
        while (__hip_atomic_load(bar, __ATOMIC_ACQUIRE, __HIP_MEMORY_SCOPE_AGENT) < expected) {
            __builtin_amdgcn_s_sleep(2);
        }
        __threadfence();  // acquire others' writes
    }
    __syncthreads();
}

// ---------------------------------------------------------------------------
// One 64-row GRU tile (non-leaf path; h either staged from `prev` or already
// present in a_lds h-region when prev==nullptr). 8 waves: wc=w&3 unit group,
// rbase=(w>>2)*32 row half; 2x2 tiles x {r,z,in,hn}.
// ---------------------------------------------------------------------------
__device__ __forceinline__ void gru_tile(
    const float* __restrict__ xg, const float* __restrict__ mg,
    const unsigned short* __restrict__ prev, unsigned short* __restrict__ outb,
    const unsigned short* __restrict__ wFrag, const float* __restrict__ bias,
    int Rb, unsigned short* a_lds)
{
    const int tid = threadIdx.x;
    // stage x: 64 rows x 32 (fp32 -> bf16)
    {
        int row = tid >> 3;
        int k4 = (tid & 7) * 4;
        float4 v = *(const float4*)(xg + (size_t)(Rb + row) * V + k4);
        unsigned int lo = (unsigned int)f2bf(v.x) | ((unsigned int)f2bf(v.y) << 16);
        unsigned int hi = (unsigned int)f2bf(v.z) | ((unsigned int)f2bf(v.w) << 16);
        uint2 p; p.x = lo; p.y = hi;
        *(uint2*)(&a_lds[row * LDA + k4]) = p;
    }
    if (prev) {
        const int node = Rb >> 7;
        const int b0 = Rb & 127;
        const unsigned short* pl = prev + ((size_t)(2 * node) * B + b0) * H;
        const unsigned short* pr = prev + ((size_t)(2 * node + 1) * B + b0) * H;
        #pragma unroll
        for (int c = 0; c < 4; ++c) {
            int f = c * NTHR + tid;
            int row = f >> 5;
            int chunk = f & 31;
            const unsigned short* src = (chunk < 16) ? (pl + row * H + chunk * 8)
                                                     : (pr + row * H + (chunk - 16) * 8);
            int4 v = *(const int4*)src;
            *(int4*)(&a_lds[row * LDA + 32 + chunk * 8]) = v;
        }
    }
    __syncthreads();

    const int lane = tid & 63;
    const int w = tid >> 6;
    const int wc = w & 3;
    const int rbase = (w >> 2) * 32;
    const int l15 = lane & 15;
    const int lg = lane >> 4;

    f32x4 zero4 = {0.f, 0.f, 0.f, 0.f};
    f32x4 acc_r[2][2], acc_z[2][2], acc_in[2][2], acc_hn[2][2];
    #pragma unroll
    for (int a = 0; a < 2; ++a)
        #pragma unroll
        for (int b = 0; b < 2; ++b) {
            acc_r[a][b] = zero4; acc_z[a][b] = zero4;
            acc_in[a][b] = zero4; acc_hn[a][b] = zero4;
        }

    // K-step 0: input x
    {
        bf16x8 a0 = *(const bf16x8*)(&a_lds[(rbase + l15) * LDA + 8 * lg]);
        bf16x8 a1 = *(const bf16x8*)(&a_lds[(rbase + 16 + l15) * LDA + 8 * lg]);
        #pragma unroll
        for (int t = 0; t < 2; ++t) {
            int tt = 2 * wc + t;
            bf16x8 br_ = *(const bf16x8*)(wFrag + ((size_t)(tt) * 64 + lane) * 8);
            bf16x8 bz_ = *(const bf16x8*)(wFrag + ((size_t)(8 + tt) * 64 + lane) * 8);
            bf16x8 bn_ = *(const bf16x8*)(wFrag + ((size_t)(16 + tt) * 64 + lane) * 8);
            acc_r[0][t] = mfma_bf16(a0, br_, acc_r[0][t]);
            acc_r[1][t] = mfma_bf16(a1, br_, acc_r[1][t]);
            acc_z[0][t] = mfma_bf16(a0, bz_, acc_z[0][t]);
            acc_z[1][t] = mfma_bf16(a1, bz_, acc_z[1][t]);
            acc_in[0][t] = mfma_bf16(a0, bn_, acc_in[0][t]);
            acc_in[1][t] = mfma_bf16(a1, bn_, acc_in[1][t]);
        }
    }
    // K-steps 1..8: hidden [h1|h2]
    #pragma unroll 2
    for (int ks = 1; ks <= 8; ++ks) {
        bf16x8 a0 = *(const bf16x8*)(&a_lds[(rbase + l15) * LDA + ks * 32 + 8 * lg]);
        bf16x8 a1 = *(const bf16x8*)(&a_lds[(rbase + 16 + l15) * LDA + ks * 32 + 8 * lg]);
        size_t fb = (size_t)ks * 24 * 64;
        #pragma unroll
        for (int t = 0; t < 2; ++t) {
            int tt = 2 * wc + t;
            bf16x8 br_ = *(const bf16x8*)(wFrag + (fb + (size_t)(tt) * 64 + lane) * 8);
            bf16x8 bz_ = *(const bf16x8*)(wFrag + (fb + (size_t)(8 + tt) * 64 + lane) * 8);
            bf16x8 bn_ = *(const bf16x8*)(wFrag + (fb + (size_t)(16 + tt) * 64 + lane) * 8);
            acc_r[0][t] = mfma_bf16(a0, br_, acc_r[0][t]);
            acc_r[1][t] = mfma_bf16(a1, br_, acc_r[1][t]);
            acc_z[0][t] = mfma_bf16(a0, bz_, acc_z[0][t]);
            acc_z[1][t] = mfma_bf16(a1, bz_, acc_z[1][t]);
            acc_hn[0][t] = mfma_bf16(a0, bn_, acc_hn[0][t]);
            acc_hn[1][t] = mfma_bf16(a1, bn_, acc_hn[1][t]);
        }
    }

    // epilogue
    #pragma unroll
    for (int t = 0; t < 2; ++t) {
        int u = wc * 32 + t * 16 + l15;
        float br = bias[u];
        float bz = bias[128 + u];
        float bin = bias[256 + u];
        float bhn = bias[384 + u];
        #pragma unroll
        for (int rt = 0; rt < 2; ++rt) {
            float4 mv = *(const float4*)(mg + Rb + rbase + rt * 16 + lg * 4);
            const float* mp = (const float*)&mv;
            #pragma unroll
            for (int reg = 0; reg < 4; ++reg) {
                int row = rbase + rt * 16 + lg * 4 + reg;
                float ar = acc_r[rt][t][reg] + br;
                float az = acc_z[rt][t][reg] + bz;
                float ain = acc_in[rt][t][reg] + bin;
                float ahn = acc_hn[rt][t][reg] + bhn;
                float rg = fast_sigmoid(ar);
                float zg = fast_sigmoid(az);
                float cg = fast_tanh(ain + rg * ahn);
                float h1 = bf2f(a_lds[row * LDA + 32 + u]);
                float h2 = bf2f(a_lds[row * LDA + 160 + u]);
                float ho = (1.f - zg) * cg + zg * 0.5f * (h1 + h2);
                outb[(size_t)(Rb + row) * H + u] = f2bf(ho * mp[reg]);
            }
        }
    }
    __syncthreads();   // a_lds safe to reuse for next tile
}

// ---------------------------------------------------------------------------
// Whole-tree persistent kernel. Grid = 256 blocks (1/CU guaranteed resident).
// Phase d=9: each tile first computes its two leaf children in-LDS.
// ---------------------------------------------------------------------------
__global__ __launch_bounds__(NTHR, 2) void tree_kernel(
    const float* __restrict__ targets, const float* __restrict__ masks,
    unsigned short* __restrict__ bufA, unsigned short* __restrict__ bufB,
    const unsigned short* __restrict__ wFrag, const float* __restrict__ bias,
    unsigned* __restrict__ bar)
{
    __shared__ __attribute__((aligned(16))) unsigned short a_lds[64 * LDA];   // 37888 B
    __shared__ __attribute__((aligned(16))) unsigned short xc_lds[128 * LDXC]; // 10240 B

    const int tid = threadIdx.x;
    const int lane = tid & 63;
    const int w = tid >> 6;
    const int l15 = lane & 15;
    const int lg = lane >> 4;

    for (int ph = 0; ph < 10; ++ph) {
        const int d = 9 - ph;
        const int tiles = 1 << (d + 1);
        const int start = (1 << d) - 1;
        const float* xg = targets + (size_t)start * B * V;
        const float* mg = masks + (size_t)start * B;
        unsigned short* outb = (d & 1) ? bufB : bufA;
        const unsigned short* prev = (d == 9) ? nullptr
                                   : (((d + 1) & 1) ? bufB : bufA);

        for (int t = blockIdx.x; t < tiles; t += NBLK) {
            const int Rb = t * 64;
            if (d == 9) {
                // ---- leaf children of node i = t>>1, batch rows b0..b0+63 ----
                const int i = t >> 1;
                const int b0 = (t & 1) * 64;
                const size_t lbase = (size_t)(1023 + 2 * i) * B;  // left child global row base
                // stage child x: 128 rows (2 children x 64) x 32 fp32 -> bf16
                #pragma unroll
                for (int c2 = 0; c2 < 2; ++c2) {
                    int task = c2 * NTHR + tid;      // 0..1023
                    int row = task >> 3;             // 0..127
                    int chunk = task & 7;
                    int child = row >> 6;
                    int rowl = row & 63;
                    float4 v = *(const float4*)(targets + (lbase + (size_t)child * B + b0 + rowl) * V + chunk * 4);
                    unsigned int lo = (unsigned int)f2bf(v.x) | ((unsigned int)f2bf(v.y) << 16);
                    unsigned int hi = (unsigned int)f2bf(v.z) | ((unsigned int)f2bf(v.w) << 16);
                    uint2 p; p.x = lo; p.y = hi;
                    *(uint2*)(&xc_lds[row * LDXC + chunk * 4]) = p;
                }
                __syncthreads();
                // child GRU: wave w -> child c=w>>2, row quarter q=w&3
                {
                    const int c = w >> 2;
                    const int q = w & 3;
                    bf16x8 af = *(const bf16x8*)(&xc_lds[(c * 64 + q * 16 + l15) * LDXC + 8 * lg]);
                    float4 mv = *(const float4*)(masks + lbase + (size_t)c * B + b0 + q * 16 + lg * 4);
                    const float* mp = (const float*)&mv;
                    #pragma unroll
                    for (int pass = 0; pass < 2; ++pass) {
                        f32x4 ar[4], az[4], an[4];
                        #pragma unroll
                        for (int t2 = 0; t2 < 4; ++t2) {
                            int tt = pass * 4 + t2;
                            bf16x8 br_ = *(const bf16x8*)(wFrag + ((size_t)(tt) * 64 + lane) * 8);
                            bf16x8 bz_ = *(const bf16x8*)(wFrag + ((size_t)(8 + tt) * 64 + lane) * 8);
                            bf16x8 bn_ = *(const bf16x8*)(wFrag + ((size_t)(16 + tt) * 64 + lane) * 8);
                            f32x4 z4 = {0.f, 0.f, 0.f, 0.f};
                            ar[t2] = mfma_bf16(af, br_, z4);
                            az[t2] = mfma_bf16(af, bz_, z4);
                            an[t2] = mfma_bf16(af, bn_, z4);
                        }
                        #pragma unroll
                        for (int t2 = 0; t2 < 4; ++t2) {
                            int u = (pass * 4 + t2) * 16 + l15;
                            float br = bias[u];
                            float bz = bias[128 + u];
                            float bin = bias[256 + u];
                            float bhn = bias[384 + u];
                            #pragma unroll
                            for (int reg = 0; reg < 4; ++reg) {
                                int rowl = q * 16 + lg * 4 + reg;
                                float rg = fast_sigmoid(ar[t2][reg] + br);
                                float zg = fast_sigmoid(az[t2][reg] + bz);
                                float cg = fast_tanh(an[t2][reg] + bin + rg * bhn);
                                float ho = (1.f - zg) * cg;
                                a_lds[rowl * LDA + 32 + c * 128 + u] = f2bf(ho * mp[reg]);
                            }
                        }
                    }
                }
                // no sync needed here: gru_tile's post-stage __syncthreads covers it
            }
            gru_tile(xg, mg, prev, outb, wFrag, bias, Rb, a_lds);
        }
        if (ph < 9) grid_barrier(bar, (unsigned)((ph + 1) * NBLK));
    }
}

// ---------------------------------------------------------------------------
// Final projection from bf16 root.
// ---------------------------------------------------------------------------
__global__ __launch_bounds__(128) void proj_kernel(
    const unsigned short* __restrict__ root,
    const float* __restrict__ mu_w, const float* __restrict__ mu_b,
    const float* __restrict__ lv_w, const float* __restrict__ lv_b,
    float* __restrict__ out)
{
    __shared__ float r_lds[H];
    int b = blockIdx.x;
    int j = threadIdx.x;
    r_lds[j] = bf2f(root[(size_t)b * H + j]);
    __syncthreads();
    float am = 0.f, al = 0.f;
    #pragma unroll 8
    for (int k = 0; k < H; ++k) {
        float rv = r_lds[k];
        am += rv * mu_w[(size_t)j * H + k];
        al += rv * lv_w[(size_t)j * H + k];
    }
    out[(size_t)b * H + j] = am + mu_b[j];
    out[(size_t)(B * H) + (size_t)b * H + j] = al + lv_b[j];
}

// ---------------------------------------------------------------------------
extern "C" void kernel_launch(void* const* d_in, const int* in_sizes, int n_in,
                              void* d_out, int out_size, void* d_ws, size_t ws_size,
                              hipStream_t stream)
{
    const float* targets = (const float*)d_in[0];
    const float* masks   = (const float*)d_in[1];
    const float* wir_w = (const float*)d_in[2];  const float* wir_b = (const float*)d_in[3];
    const float* whr_w = (const float*)d_in[4];  const float* whr_b = (const float*)d_in[5];
    const float* wiz_w = (const float*)d_in[6];  const float* wiz_b = (const float*)d_in[7];
    const float* win_w = (const float*)d_in[10]; const float* win_b = (const float*)d_in[11];
    const float* whz_w = (const float*)d_in[8];  const float* whz_b = (const float*)d_in[9];
    const float* whn_w = (const float*)d_in[12]; const float* whn_b = (const float*)d_in[13];
    const float* mu_w  = (const float*)d_in[14]; const float* mu_b  = (const float*)d_in[15];
    const float* lv_w  = (const float*)d_in[16]; const float* lv_b  = (const float*)d_in[17];

    unsigned short* bufA  = (unsigned short*)d_ws;     // even levels (up to 512*128 rows used)
    unsigned short* bufB  = bufA + 16777216;           // odd levels
    unsigned short* wFrag = bufB + 8388608;            // 9*24*64*8 bf16
    float*          biasw = (float*)(wFrag + 110592);  // 4*128 fp32
    unsigned*       bar   = (unsigned*)(biasw + 512);  // grid barrier counter

    prep_pack<<<54, 256, 0, stream>>>(
        wir_w, whr_w, wiz_w, whz_w, win_w, whn_w,
        wir_b, whr_b, wiz_b, whz_b, win_b, whn_b, wFrag, biasw, bar);

    tree_kernel<<<NBLK, NTHR, 0, stream>>>(targets, masks, bufA, bufB, wFrag, biasw, bar);

    proj_kernel<<<128, 128, 0, stream>>>(bufA, mu_w, mu_b, lv_w, lv_b, (float*)d_out);
}

// Round 5
// 308.848 us; speedup vs baseline: 1.8270x; 1.8270x over previous
//
#include <hip/hip_runtime.h>
#include <hip/hip_bf16.h>
#include <math.h>

#define B 128
#define V 32
#define H 128
#define LDA 296    // padded A row pitch in bf16 elems (592 B)
#define LDXC 40    // child-x row pitch in bf16 elems (80 B, 16B-aligned)
#define NBLK 256
#define NTHR 512

typedef __attribute__((ext_vector_type(8))) short bf16x8;
typedef __attribute__((ext_vector_type(4))) float f32x4;

__device__ inline f32x4 mfma_bf16(bf16x8 a, bf16x8 b, f32x4 c) {
    return __builtin_amdgcn_mfma_f32_16x16x32_bf16(a, b, c, 0, 0, 0);
}
__device__ inline unsigned short f2bf(float f) {
    __hip_bfloat16 h = __float2bfloat16(f);
    return __builtin_bit_cast(unsigned short, h);
}
__device__ inline float bf2f(unsigned short u) {
    unsigned int x = ((unsigned int)u) << 16;
    return __builtin_bit_cast(float, x);
}
__device__ inline float fast_sigmoid(float x) {
    float e = __builtin_amdgcn_exp2f(x * -1.44269504f);
    return __builtin_amdgcn_rcpf(1.f + e);
}
__device__ inline float fast_tanh(float x) {
    float e = __builtin_amdgcn_exp2f(x * 2.88539008f);   // exp(2x)
    return 1.f - 2.f * __builtin_amdgcn_rcpf(e + 1.f);
}

// ---------------------------------------------------------------------------
// Pack weights into MFMA B-fragment order + combined biases; zero the barrier.
// ---------------------------------------------------------------------------
__global__ void prep_pack(const float* __restrict__ wir_w, const float* __restrict__ whr_w,
                          const float* __restrict__ wiz_w, const float* __restrict__ whz_w,
                          const float* __restrict__ win_w, const float* __restrict__ whn_w,
                          const float* __restrict__ wir_b, const float* __restrict__ whr_b,
                          const float* __restrict__ wiz_b, const float* __restrict__ whz_b,
                          const float* __restrict__ win_b, const float* __restrict__ whn_b,
                          unsigned short* __restrict__ wFrag, float* __restrict__ bias,
                          unsigned* __restrict__ bar)
{
    int idx = blockIdx.x * blockDim.x + threadIdx.x;
    if (idx == 0) *bar = 0u;
    if (idx < 9 * 24 * 64) {
        int lane = idx & 63;
        int ctks = idx >> 6;
        int ct = ctks % 24;
        int ks = ctks / 24;
        int g = ct >> 3;
        int t = ct & 7;
        int u = t * 16 + (lane & 15);
        const float* wi = (g == 0) ? wir_w : (g == 1) ? wiz_w : win_w;
        const float* wh = (g == 0) ? whr_w : (g == 1) ? whz_w : whn_w;
        unsigned short v[8] __attribute__((aligned(16)));
        #pragma unroll
        for (int i = 0; i < 8; ++i) {
            float f;
            if (ks == 0) { int k = 8 * (lane >> 4) + i; f = wi[u * V + k]; }
            else         { int k = (ks - 1) * 32 + 8 * (lane >> 4) + i; f = wh[u * 256 + k]; }
            v[i] = f2bf(f);
        }
        *(int4*)(wFrag + (size_t)idx * 8) = *(const int4*)v;
    }
    if (idx < 4 * H) {
        int s = idx / H, u = idx % H;
        float val;
        if (s == 0)      val = wir_b[u] + whr_b[u];
        else if (s == 1) val = wiz_b[u] + whz_b[u];
        else if (s == 2) val = win_b[u];
        else             val = whn_b[u];
        bias[idx] = val;
    }
}

// ---------------------------------------------------------------------------
// Grid barrier, low-contention: RELAXED poll (no per-poll cache maintenance),
// s_sleep backoff; one release fence before the add, one acquire fence after.
// ---------------------------------------------------------------------------
__device__ inline void grid_barrier(unsigned* bar, unsigned expected) {
    __syncthreads();
    if (threadIdx.x == 0) {
        __threadfence();   // release our global writes
        __hip_atomic_fetch_add(bar, 1u, __ATOMIC_RELAXED, __HIP_MEMORY_SCOPE_AGENT);
        while (__hip_atomic_load(bar, __ATOMIC_RELAXED, __HIP_MEMORY_SCOPE_AGENT) < expected) {
            __builtin_amdgcn_s_sleep(16);
        }
        __threadfence();   // acquire others' writes
    }
    __syncthreads();
}

// ---------------------------------------------------------------------------
// One 64-row GRU tile. prev==nullptr => h-region of a_lds already filled.
// 8 waves: wc=w&3 unit group, rbase=(w>>2)*32 row half; 2x2 x {r,z,in,hn}.
// ---------------------------------------------------------------------------
__device__ __forceinline__ void gru_tile(
    const float* __restrict__ xg, const float* __restrict__ mg,
    const unsigned short* __restrict__ prev, unsigned short* __restrict__ outb,
    const unsigned short* __restrict__ wFrag, const float* __restrict__ bias,
    int Rb, unsigned short* a_lds)
{
    const int tid = threadIdx.x;
    {
        int row = tid >> 3;
        int k4 = (tid & 7) * 4;
        float4 v = *(const float4*)(xg + (size_t)(Rb + row) * V + k4);
        unsigned int lo = (unsigned int)f2bf(v.x) | ((unsigned int)f2bf(v.y) << 16);
        unsigned int hi = (unsigned int)f2bf(v.z) | ((unsigned int)f2bf(v.w) << 16);
        uint2 p; p.x = lo; p.y = hi;
        *(uint2*)(&a_lds[row * LDA + k4]) = p;
    }
    if (prev) {
        const int node = Rb >> 7;
        const int b0 = Rb & 127;
        const unsigned short* pl = prev + ((size_t)(2 * node) * B + b0) * H;
        const unsigned short* pr = prev + ((size_t)(2 * node + 1) * B + b0) * H;
        #pragma unroll
        for (int c = 0; c < 4; ++c) {
            int f = c * NTHR + tid;
            int row = f >> 5;
            int chunk = f & 31;
            const unsigned short* src = (chunk < 16) ? (pl + row * H + chunk * 8)
                                                     : (pr + row * H + (chunk - 16) * 8);
            int4 v = *(const int4*)src;
            *(int4*)(&a_lds[row * LDA + 32 + chunk * 8]) = v;
        }
    }
    __syncthreads();

    const int lane = tid & 63;
    const int w = tid >> 6;
    const int wc = w & 3;
    const int rbase = (w >> 2) * 32;
    const int l15 = lane & 15;
    const int lg = lane >> 4;

    f32x4 zero4 = {0.f, 0.f, 0.f, 0.f};
    f32x4 acc_r[2][2], acc_z[2][2], acc_in[2][2], acc_hn[2][2];
    #pragma unroll
    for (int a = 0; a < 2; ++a)
        #pragma unroll
        for (int b = 0; b < 2; ++b) {
            acc_r[a][b] = zero4; acc_z[a][b] = zero4;
            acc_in[a][b] = zero4; acc_hn[a][b] = zero4;
        }

    // K-step 0: input x
    {
        bf16x8 a0 = *(const bf16x8*)(&a_lds[(rbase + l15) * LDA + 8 * lg]);
        bf16x8 a1 = *(const bf16x8*)(&a_lds[(rbase + 16 + l15) * LDA + 8 * lg]);
        #pragma unroll
        for (int t = 0; t < 2; ++t) {
            int tt = 2 * wc + t;
            bf16x8 br_ = *(const bf16x8*)(wFrag + ((size_t)(tt) * 64 + lane) * 8);
            bf16x8 bz_ = *(const bf16x8*)(wFrag + ((size_t)(8 + tt) * 64 + lane) * 8);
            bf16x8 bn_ = *(const bf16x8*)(wFrag + ((size_t)(16 + tt) * 64 + lane) * 8);
            acc_r[0][t] = mfma_bf16(a0, br_, acc_r[0][t]);
            acc_r[1][t] = mfma_bf16(a1, br_, acc_r[1][t]);
            acc_z[0][t] = mfma_bf16(a0, bz_, acc_z[0][t]);
            acc_z[1][t] = mfma_bf16(a1, bz_, acc_z[1][t]);
            acc_in[0][t] = mfma_bf16(a0, bn_, acc_in[0][t]);
            acc_in[1][t] = mfma_bf16(a1, bn_, acc_in[1][t]);
        }
    }
    // K-steps 1..8: hidden [h1|h2]
    #pragma unroll 2
    for (int ks = 1; ks <= 8; ++ks) {
        bf16x8 a0 = *(const bf16x8*)(&a_lds[(rbase + l15) * LDA + ks * 32 + 8 * lg]);
        bf16x8 a1 = *(const bf16x8*)(&a_lds[(rbase + 16 + l15) * LDA + ks * 32 + 8 * lg]);
        size_t fb = (size_t)ks * 24 * 64;
        #pragma unroll
        for (int t = 0; t < 2; ++t) {
            int tt = 2 * wc + t;
            bf16x8 br_ = *(const bf16x8*)(wFrag + (fb + (size_t)(tt) * 64 + lane) * 8);
            bf16x8 bz_ = *(const bf16x8*)(wFrag + (fb + (size_t)(8 + tt) * 64 + lane) * 8);
            bf16x8 bn_ = *(const bf16x8*)(wFrag + (fb + (size_t)(16 + tt) * 64 + lane) * 8);
            acc_r[0][t] = mfma_bf16(a0, br_, acc_r[0][t]);
            acc_r[1][t] = mfma_bf16(a1, br_, acc_r[1][t]);
            acc_z[0][t] = mfma_bf16(a0, bz_, acc_z[0][t]);
            acc_z[1][t] = mfma_bf16(a1, bz_, acc_z[1][t]);
            acc_hn[0][t] = mfma_bf16(a0, bn_, acc_hn[0][t]);
            acc_hn[1][t] = mfma_bf16(a1, bn_, acc_hn[1][t]);
        }
    }

    // epilogue
    #pragma unroll
    for (int t = 0; t < 2; ++t) {
        int u = wc * 32 + t * 16 + l15;
        float br = bias[u];
        float bz = bias[128 + u];
        float bin = bias[256 + u];
        float bhn = bias[384 + u];
        #pragma unroll
        for (int rt = 0; rt < 2; ++rt) {
            float4 mv = *(const float4*)(mg + Rb + rbase + rt * 16 + lg * 4);
            const float* mp = (const float*)&mv;
            #pragma unroll
            for (int reg = 0; reg < 4; ++reg) {
                int row = rbase + rt * 16 + lg * 4 + reg;
                float ar = acc_r[rt][t][reg] + br;
                float az = acc_z[rt][t][reg] + bz;
                float ain = acc_in[rt][t][reg] + bin;
                float ahn = acc_hn[rt][t][reg] + bhn;
                float rg = fast_sigmoid(ar);
                float zg = fast_sigmoid(az);
                float cg = fast_tanh(ain + rg * ahn);
                float h1 = bf2f(a_lds[row * LDA + 32 + u]);
                float h2 = bf2f(a_lds[row * LDA + 160 + u]);
                float ho = (1.f - zg) * cg + zg * 0.5f * (h1 + h2);
                outb[(size_t)(Rb + row) * H + u] = f2bf(ho * mp[reg]);
            }
        }
    }
    __syncthreads();   // a_lds/xc_lds safe to reuse for next tile
}

// ---------------------------------------------------------------------------
// Whole-tree persistent kernel. Grid = 256 blocks (1/CU).
// Phase A: block b owns the depth-8 subtree of node b:
//   4 x (leaf-pair -> d9 tile), 2 x d8 tile — ZERO grid barriers (87.5% of
//   FLOPs), d8 reads d9 rows this block just wrote (own-L2 hits).
// Tail: d=7..0 with one grid barrier before each phase (8 total).
// ---------------------------------------------------------------------------
__global__ __launch_bounds__(NTHR, 2) void tree_kernel(
    const float* __restrict__ targets, const float* __restrict__ masks,
    unsigned short* __restrict__ bufA, unsigned short* __restrict__ bufB,
    const unsigned short* __restrict__ wFrag, const float* __restrict__ bias,
    unsigned* __restrict__ bar)
{
    __shared__ __attribute__((aligned(16))) unsigned short a_lds[64 * LDA];    // 37888 B
    __shared__ __attribute__((aligned(16))) unsigned short xc_lds[128 * LDXC]; // 10240 B

    const int tid = threadIdx.x;
    const int lane = tid & 63;
    const int w = tid >> 6;
    const int l15 = lane & 15;
    const int lg = lane >> 4;

    // ================= Phase A: subtree of depth-8 node b =================
    {
        const int blk = blockIdx.x;
        const float* xg9 = targets + (size_t)511 * B * V;
        const float* mg9 = masks + (size_t)511 * B;
        for (int s = 0; s < 4; ++s) {
            const int t = 4 * blk + s;       // d9 tile index (node t>>1, half t&1)
            const int Rb = t * 64;
            const int i = t >> 1;
            const int b0 = (t & 1) * 64;
            const size_t lbase = (size_t)(1023 + 2 * i) * B;   // left leaf child rows
            // stage child x: 128 rows (2 children x 64) x 32 fp32 -> bf16
            #pragma unroll
            for (int c2 = 0; c2 < 2; ++c2) {
                int task = c2 * NTHR + tid;
                int row = task >> 3;
                int chunk = task & 7;
                int child = row >> 6;
                int rowl = row & 63;
                float4 v = *(const float4*)(targets + (lbase + (size_t)child * B + b0 + rowl) * V + chunk * 4);
                unsigned int lo = (unsigned int)f2bf(v.x) | ((unsigned int)f2bf(v.y) << 16);
                unsigned int hi = (unsigned int)f2bf(v.z) | ((unsigned int)f2bf(v.w) << 16);
                uint2 p; p.x = lo; p.y = hi;
                *(uint2*)(&xc_lds[row * LDXC + chunk * 4]) = p;
            }
            __syncthreads();
            // child GRU: wave w -> child c=w>>2, row quarter q=w&3
            {
                const int c = w >> 2;
                const int q = w & 3;
                bf16x8 af = *(const bf16x8*)(&xc_lds[(c * 64 + q * 16 + l15) * LDXC + 8 * lg]);
                float4 mv = *(const float4*)(masks + lbase + (size_t)c * B + b0 + q * 16 + lg * 4);
                const float* mp = (const float*)&mv;
                #pragma unroll
                for (int pass = 0; pass < 2; ++pass) {
                    f32x4 ar[4], az[4], an[4];
                    #pragma unroll
                    for (int t2 = 0; t2 < 4; ++t2) {
                        int tt = pass * 4 + t2;
                        bf16x8 br_ = *(const bf16x8*)(wFrag + ((size_t)(tt) * 64 + lane) * 8);
                        bf16x8 bz_ = *(const bf16x8*)(wFrag + ((size_t)(8 + tt) * 64 + lane) * 8);
                        bf16x8 bn_ = *(const bf16x8*)(wFrag + ((size_t)(16 + tt) * 64 + lane) * 8);
                        f32x4 z4 = {0.f, 0.f, 0.f, 0.f};
                        ar[t2] = mfma_bf16(af, br_, z4);
                        az[t2] = mfma_bf16(af, bz_, z4);
                        an[t2] = mfma_bf16(af, bn_, z4);
                    }
                    #pragma unroll
                    for (int t2 = 0; t2 < 4; ++t2) {
                        int u = (pass * 4 + t2) * 16 + l15;
                        float br = bias[u];
                        float bz = bias[128 + u];
                        float bin = bias[256 + u];
                        float bhn = bias[384 + u];
                        #pragma unroll
                        for (int reg = 0; reg < 4; ++reg) {
                            int rowl = q * 16 + lg * 4 + reg;
                            float rg = fast_sigmoid(ar[t2][reg] + br);
                            float zg = fast_sigmoid(az[t2][reg] + bz);
                            float cg = fast_tanh(an[t2][reg] + bin + rg * bhn);
                            float ho = (1.f - zg) * cg;
                            a_lds[rowl * LDA + 32 + c * 128 + u] = f2bf(ho * mp[reg]);
                        }
                    }
                }
            }
            gru_tile(xg9, mg9, nullptr, bufB, wFrag, bias, Rb, a_lds);
        }
        // d8 tiles of node blk: read bufB rows this block just wrote
        const float* xg8 = targets + (size_t)255 * B * V;
        const float* mg8 = masks + (size_t)255 * B;
        for (int s = 0; s < 2; ++s) {
            const int Rb = (2 * blk + s) * 64;
            gru_tile(xg8, mg8, bufB, bufA, wFrag, bias, Rb, a_lds);
        }
    }

    // ================= Tail: d = 7..0 with grid barriers =================
    unsigned expd = 0;
    for (int d = 7; d >= 0; --d) {
        expd += NBLK;
        grid_barrier(bar, expd);
        const int tiles = 1 << (d + 1);
        const int start = (1 << d) - 1;
        const float* xg = targets + (size_t)start * B * V;
        const float* mg = masks + (size_t)start * B;
        unsigned short* outb = (d & 1) ? bufB : bufA;
        const unsigned short* prev = ((d + 1) & 1) ? bufB : bufA;
        for (int t = blockIdx.x; t < tiles; t += NBLK) {
            gru_tile(xg, mg, prev, outb, wFrag, bias, t * 64, a_lds);
        }
    }
}

// ---------------------------------------------------------------------------
// Final projection from bf16 root.
// ---------------------------------------------------------------------------
__global__ __launch_bounds__(128) void proj_kernel(
    const unsigned short* __restrict__ root,
    const float* __restrict__ mu_w, const float* __restrict__ mu_b,
    const float* __restrict__ lv_w, const float* __restrict__ lv_b,
    float* __restrict__ out)
{
    __shared__ float r_lds[H];
    int b = blockIdx.x;
    int j = threadIdx.x;
    r_lds[j] = bf2f(root[(size_t)b * H + j]);
    __syncthreads();
    float am = 0.f, al = 0.f;
    #pragma unroll 8
    for (int k = 0; k < H; ++k) {
        float rv = r_lds[k];
        am += rv * mu_w[(size_t)j * H + k];
        al += rv * lv_w[(size_t)j * H + k];
    }
    out[(size_t)b * H + j] = am + mu_b[j];
    out[(size_t)(B * H) + (size_t)b * H + j] = al + lv_b[j];
}

// ---------------------------------------------------------------------------
extern "C" void kernel_launch(void* const* d_in, const int* in_sizes, int n_in,
                              void* d_out, int out_size, void* d_ws, size_t ws_size,
                              hipStream_t stream)
{
    const float* targets = (const float*)d_in[0];
    const float* masks   = (const float*)d_in[1];
    const float* wir_w = (const float*)d_in[2];  const float* wir_b = (const float*)d_in[3];
    const float* whr_w = (const float*)d_in[4];  const float* whr_b = (const float*)d_in[5];
    const float* wiz_w = (const float*)d_in[6];  const float* wiz_b = (const float*)d_in[7];
    const float* whz_w = (const float*)d_in[8];  const float* whz_b = (const float*)d_in[9];
    const float* win_w = (const float*)d_in[10]; const float* win_b = (const float*)d_in[11];
    const float* whn_w = (const float*)d_in[12]; const float* whn_b = (const float*)d_in[13];
    const float* mu_w  = (const float*)d_in[14]; const float* mu_b  = (const float*)d_in[15];
    const float* lv_w  = (const float*)d_in[16]; const float* lv_b  = (const float*)d_in[17];

    unsigned short* bufA  = (unsigned short*)d_ws;     // even levels
    unsigned short* bufB  = bufA + 16777216;           // odd levels
    unsigned short* wFrag = bufB + 8388608;            // 9*24*64*8 bf16
    float*          biasw = (float*)(wFrag + 110592);  // 4*128 fp32
    unsigned*       bar   = (unsigned*)(biasw + 512);  // grid barrier counter

    prep_pack<<<54, 256, 0, stream>>>(
        wir_w, whr_w, wiz_w, whz_w, win_w, whn_w,
        wir_b, whr_b, wiz_b, whz_b, win_b, whn_b, wFrag, biasw, bar);

    tree_kernel<<<NBLK, NTHR, 0, stream>>>(targets, masks, bufA, bufB, wFrag, biasw, bar);

    proj_kernel<<<128, 128, 0, stream>>>(bufA, mu_w, mu_b, lv_w, lv_b, (float*)d_out);
}

// Round 6
// 159.923 us; speedup vs baseline: 3.5284x; 1.9312x over previous
//
#include <hip/hip_runtime.h>
#include <hip/hip_bf16.h>
#include <math.h>

#define B 128
#define V 32
#define H 128
#define LDA 296    // padded A row pitch in bf16 elems (592 B)
#define LDXC 40    // child-x row pitch in bf16 elems (80 B, 16B-aligned)
#define NTHR 512

typedef __attribute__((ext_vector_type(8))) short bf16x8;
typedef __attribute__((ext_vector_type(4))) float f32x4;

__device__ inline f32x4 mfma_bf16(bf16x8 a, bf16x8 b, f32x4 c) {
    return __builtin_amdgcn_mfma_f32_16x16x32_bf16(a, b, c, 0, 0, 0);
}
__device__ inline unsigned short f2bf(float f) {
    __hip_bfloat16 h = __float2bfloat16(f);
    return __builtin_bit_cast(unsigned short, h);
}
__device__ inline float bf2f(unsigned short u) {
    unsigned int x = ((unsigned int)u) << 16;
    return __builtin_bit_cast(float, x);
}
__device__ inline float fast_sigmoid(float x) {
    float e = __builtin_amdgcn_exp2f(x * -1.44269504f);
    return __builtin_amdgcn_rcpf(1.f + e);
}
__device__ inline float fast_tanh(float x) {
    float e = __builtin_amdgcn_exp2f(x * 2.88539008f);   // exp(2x)
    return 1.f - 2.f * __builtin_amdgcn_rcpf(e + 1.f);
}

// ---------------------------------------------------------------------------
// Pack weights into MFMA B-fragment order + combined biases.
// frag index = (ks*24 + g*8 + t)*64 + lane; same (lane,elem)->k map as A-frags.
// ---------------------------------------------------------------------------
__global__ void prep_pack(const float* __restrict__ wir_w, const float* __restrict__ whr_w,
                          const float* __restrict__ wiz_w, const float* __restrict__ whz_w,
                          const float* __restrict__ win_w, const float* __restrict__ whn_w,
                          const float* __restrict__ wir_b, const float* __restrict__ whr_b,
                          const float* __restrict__ wiz_b, const float* __restrict__ whz_b,
                          const float* __restrict__ win_b, const float* __restrict__ whn_b,
                          unsigned short* __restrict__ wFrag, float* __restrict__ bias)
{
    int idx = blockIdx.x * blockDim.x + threadIdx.x;
    if (idx < 9 * 24 * 64) {
        int lane = idx & 63;
        int ctks = idx >> 6;
        int ct = ctks % 24;
        int ks = ctks / 24;
        int g = ct >> 3;
        int t = ct & 7;
        int u = t * 16 + (lane & 15);
        const float* wi = (g == 0) ? wir_w : (g == 1) ? wiz_w : win_w;
        const float* wh = (g == 0) ? whr_w : (g == 1) ? whz_w : whn_w;
        unsigned short v[8] __attribute__((aligned(16)));
        #pragma unroll
        for (int i = 0; i < 8; ++i) {
            float f;
            if (ks == 0) { int k = 8 * (lane >> 4) + i; f = wi[u * V + k]; }
            else         { int k = (ks - 1) * 32 + 8 * (lane >> 4) + i; f = wh[u * 256 + k]; }
            v[i] = f2bf(f);
        }
        *(int4*)(wFrag + (size_t)idx * 8) = *(const int4*)v;
    }
    if (idx < 4 * H) {
        int s = idx / H, u = idx % H;
        float val;
        if (s == 0)      val = wir_b[u] + whr_b[u];
        else if (s == 1) val = wiz_b[u] + whz_b[u];
        else if (s == 2) val = win_b[u];
        else             val = whn_b[u];
        bias[idx] = val;
    }
}

// ---------------------------------------------------------------------------
// One 64-row GRU tile. prev==nullptr => h-region of a_lds already filled.
// 8 waves: wc=w&3 unit group, rbase=(w>>2)*32 row half; 2x2 x {r,z,in,hn}.
// Ends with __syncthreads (which drains vmcnt first), so a following tile in
// the same block may safely read this tile's global output through own-L2.
// ---------------------------------------------------------------------------
__device__ __forceinline__ void gru_tile(
    const float* __restrict__ xg, const float* __restrict__ mg,
    const unsigned short* __restrict__ prev, unsigned short* __restrict__ outb,
    const unsigned short* __restrict__ wFrag, const float* __restrict__ bias,
    int Rb, unsigned short* a_lds)
{
    const int tid = threadIdx.x;
    {
        int row = tid >> 3;
        int k4 = (tid & 7) * 4;
        float4 v = *(const float4*)(xg + (size_t)(Rb + row) * V + k4);
        unsigned int lo = (unsigned int)f2bf(v.x) | ((unsigned int)f2bf(v.y) << 16);
        unsigned int hi = (unsigned int)f2bf(v.z) | ((unsigned int)f2bf(v.w) << 16);
        uint2 p; p.x = lo; p.y = hi;
        *(uint2*)(&a_lds[row * LDA + k4]) = p;
    }
    if (prev) {
        const int node = Rb >> 7;
        const int b0 = Rb & 127;
        const unsigned short* pl = prev + ((size_t)(2 * node) * B + b0) * H;
        const unsigned short* pr = prev + ((size_t)(2 * node + 1) * B + b0) * H;
        #pragma unroll
        for (int c = 0; c < 4; ++c) {
            int f = c * NTHR + tid;
            int row = f >> 5;
            int chunk = f & 31;
            const unsigned short* src = (chunk < 16) ? (pl + row * H + chunk * 8)
                                                     : (pr + row * H + (chunk - 16) * 8);
            int4 v = *(const int4*)src;
            *(int4*)(&a_lds[row * LDA + 32 + chunk * 8]) = v;
        }
    }
    __syncthreads();

    const int lane = tid & 63;
    const int w = tid >> 6;
    const int wc = w & 3;
    const int rbase = (w >> 2) * 32;
    const int l15 = lane & 15;
    const int lg = lane >> 4;

    f32x4 zero4 = {0.f, 0.f, 0.f, 0.f};
    f32x4 acc_r[2][2], acc_z[2][2], acc_in[2][2], acc_hn[2][2];
    #pragma unroll
    for (int a = 0; a < 2; ++a)
        #pragma unroll
        for (int b = 0; b < 2; ++b) {
            acc_r[a][b] = zero4; acc_z[a][b] = zero4;
            acc_in[a][b] = zero4; acc_hn[a][b] = zero4;
        }

    // K-step 0: input x
    {
        bf16x8 a0 = *(const bf16x8*)(&a_lds[(rbase + l15) * LDA + 8 * lg]);
        bf16x8 a1 = *(const bf16x8*)(&a_lds[(rbase + 16 + l15) * LDA + 8 * lg]);
        #pragma unroll
        for (int t = 0; t < 2; ++t) {
            int tt = 2 * wc + t;
            bf16x8 br_ = *(const bf16x8*)(wFrag + ((size_t)(tt) * 64 + lane) * 8);
            bf16x8 bz_ = *(const bf16x8*)(wFrag + ((size_t)(8 + tt) * 64 + lane) * 8);
            bf16x8 bn_ = *(const bf16x8*)(wFrag + ((size_t)(16 + tt) * 64 + lane) * 8);
            acc_r[0][t] = mfma_bf16(a0, br_, acc_r[0][t]);
            acc_r[1][t] = mfma_bf16(a1, br_, acc_r[1][t]);
            acc_z[0][t] = mfma_bf16(a0, bz_, acc_z[0][t]);
            acc_z[1][t] = mfma_bf16(a1, bz_, acc_z[1][t]);
            acc_in[0][t] = mfma_bf16(a0, bn_, acc_in[0][t]);
            acc_in[1][t] = mfma_bf16(a1, bn_, acc_in[1][t]);
        }
    }
    // K-steps 1..8: hidden [h1|h2]
    #pragma unroll 2
    for (int ks = 1; ks <= 8; ++ks) {
        bf16x8 a0 = *(const bf16x8*)(&a_lds[(rbase + l15) * LDA + ks * 32 + 8 * lg]);
        bf16x8 a1 = *(const bf16x8*)(&a_lds[(rbase + 16 + l15) * LDA + ks * 32 + 8 * lg]);
        size_t fb = (size_t)ks * 24 * 64;
        #pragma unroll
        for (int t = 0; t < 2; ++t) {
            int tt = 2 * wc + t;
            bf16x8 br_ = *(const bf16x8*)(wFrag + (fb + (size_t)(tt) * 64 + lane) * 8);
            bf16x8 bz_ = *(const bf16x8*)(wFrag + (fb + (size_t)(8 + tt) * 64 + lane) * 8);
            bf16x8 bn_ = *(const bf16x8*)(wFrag + (fb + (size_t)(16 + tt) * 64 + lane) * 8);
            acc_r[0][t] = mfma_bf16(a0, br_, acc_r[0][t]);
            acc_r[1][t] = mfma_bf16(a1, br_, acc_r[1][t]);
            acc_z[0][t] = mfma_bf16(a0, bz_, acc_z[0][t]);
            acc_z[1][t] = mfma_bf16(a1, bz_, acc_z[1][t]);
            acc_hn[0][t] = mfma_bf16(a0, bn_, acc_hn[0][t]);
            acc_hn[1][t] = mfma_bf16(a1, bn_, acc_hn[1][t]);
        }
    }

    // epilogue
    #pragma unroll
    for (int t = 0; t < 2; ++t) {
        int u = wc * 32 + t * 16 + l15;
        float br = bias[u];
        float bz = bias[128 + u];
        float bin = bias[256 + u];
        float bhn = bias[384 + u];
        #pragma unroll
        for (int rt = 0; rt < 2; ++rt) {
            float4 mv = *(const float4*)(mg + Rb + rbase + rt * 16 + lg * 4);
            const float* mp = (const float*)&mv;
            #pragma unroll
            for (int reg = 0; reg < 4; ++reg) {
                int row = rbase + rt * 16 + lg * 4 + reg;
                float ar = acc_r[rt][t][reg] + br;
                float az = acc_z[rt][t][reg] + bz;
                float ain = acc_in[rt][t][reg] + bin;
                float ahn = acc_hn[rt][t][reg] + bhn;
                float rg = fast_sigmoid(ar);
                float zg = fast_sigmoid(az);
                float cg = fast_tanh(ain + rg * ahn);
                float h1 = bf2f(a_lds[row * LDA + 32 + u]);
                float h2 = bf2f(a_lds[row * LDA + 160 + u]);
                float ho = (1.f - zg) * cg + zg * 0.5f * (h1 + h2);
                outb[(size_t)(Rb + row) * H + u] = f2bf(ho * mp[reg]);
            }
        }
    }
    __syncthreads();   // drains vmcnt; a_lds/xc_lds reusable, out visible to own CU
}

// ---------------------------------------------------------------------------
// Leaf pair of d9 local node j, batch half b0: compute 2x64 child hiddens
// straight into a_lds h-region ([h1|h2] layout). No global round-trip.
// ---------------------------------------------------------------------------
__device__ __forceinline__ void leaf_pair(
    const float* __restrict__ targets, const float* __restrict__ masks,
    const unsigned short* __restrict__ wFrag, const float* __restrict__ bias,
    int j, int b0, unsigned short* a_lds, unsigned short* xc_lds)
{
    const int tid = threadIdx.x;
    const int lane = tid & 63;
    const int w = tid >> 6;
    const int l15 = lane & 15;
    const int lg = lane >> 4;
    const size_t lbase = (size_t)(1023 + 2 * j) * B;   // left leaf child rows

    // stage child x: 128 rows (2 children x 64) x 32 fp32 -> bf16
    #pragma unroll
    for (int c2 = 0; c2 < 2; ++c2) {
        int task = c2 * NTHR + tid;
        int row = task >> 3;
        int chunk = task & 7;
        int child = row >> 6;
        int rowl = row & 63;
        float4 v = *(const float4*)(targets + (lbase + (size_t)child * B + b0 + rowl) * V + chunk * 4);
        unsigned int lo = (unsigned int)f2bf(v.x) | ((unsigned int)f2bf(v.y) << 16);
        unsigned int hi = (unsigned int)f2bf(v.z) | ((unsigned int)f2bf(v.w) << 16);
        uint2 p; p.x = lo; p.y = hi;
        *(uint2*)(&xc_lds[row * LDXC + chunk * 4]) = p;
    }
    __syncthreads();
    // child GRU: wave w -> child c=w>>2, row quarter q=w&3
    const int c = w >> 2;
    const int q = w & 3;
    bf16x8 af = *(const bf16x8*)(&xc_lds[(c * 64 + q * 16 + l15) * LDXC + 8 * lg]);
    float4 mv = *(const float4*)(masks + lbase + (size_t)c * B + b0 + q * 16 + lg * 4);
    const float* mp = (const float*)&mv;
    #pragma unroll
    for (int pass = 0; pass < 2; ++pass) {
        f32x4 ar[4], az[4], an[4];
        #pragma unroll
        for (int t2 = 0; t2 < 4; ++t2) {
            int tt = pass * 4 + t2;
            bf16x8 br_ = *(const bf16x8*)(wFrag + ((size_t)(tt) * 64 + lane) * 8);
            bf16x8 bz_ = *(const bf16x8*)(wFrag + ((size_t)(8 + tt) * 64 + lane) * 8);
            bf16x8 bn_ = *(const bf16x8*)(wFrag + ((size_t)(16 + tt) * 64 + lane) * 8);
            f32x4 z4 = {0.f, 0.f, 0.f, 0.f};
            ar[t2] = mfma_bf16(af, br_, z4);
            az[t2] = mfma_bf16(af, bz_, z4);
            an[t2] = mfma_bf16(af, bn_, z4);
        }
        #pragma unroll
        for (int t2 = 0; t2 < 4; ++t2) {
            int u = (pass * 4 + t2) * 16 + l15;
            float br = bias[u];
            float bz = bias[128 + u];
            float bin = bias[256 + u];
            float bhn = bias[384 + u];
            #pragma unroll
            for (int reg = 0; reg < 4; ++reg) {
                int rowl = q * 16 + lg * 4 + reg;
                float rg = fast_sigmoid(ar[t2][reg] + br);
                float zg = fast_sigmoid(az[t2][reg] + bz);
                float cg = fast_tanh(an[t2][reg] + bin + rg * bhn);
                float ho = (1.f - zg) * cg;
                a_lds[rowl * LDA + 32 + c * 128 + u] = f2bf(ho * mp[reg]);
            }
        }
    }
    // no sync needed: gru_tile's post-stage __syncthreads covers the h-region
}

// ---------------------------------------------------------------------------
// Subtree kernel: grid 512. Block bb (i=bb>>1 d8 node, s=bb&1 batch half):
//   2 x { leaf_pair -> d9 gru_tile }, then the d8 tile consuming exactly
//   those two d9 tiles (own-L2 reads, ordered by gru_tile's end barrier).
// ---------------------------------------------------------------------------
__global__ __launch_bounds__(NTHR, 2) void subtree_kernel(
    const float* __restrict__ targets, const float* __restrict__ masks,
    unsigned short* __restrict__ lvl9, unsigned short* __restrict__ lvl8,
    const unsigned short* __restrict__ wFrag, const float* __restrict__ bias)
{
    __shared__ __attribute__((aligned(16))) unsigned short a_lds[64 * LDA];    // 37888 B
    __shared__ __attribute__((aligned(16))) unsigned short xc_lds[128 * LDXC]; // 10240 B

    const int bb = blockIdx.x;
    const int i = bb >> 1;
    const int s = bb & 1;

    const float* xg9 = targets + (size_t)511 * B * V;
    const float* mg9 = masks + (size_t)511 * B;
    #pragma unroll
    for (int q2 = 0; q2 < 2; ++q2) {
        const int j = 2 * i + q2;        // d9 local node
        const int t = 2 * j + s;         // d9 tile index
        leaf_pair(targets, masks, wFrag, bias, j, s * 64, a_lds, xc_lds);
        gru_tile(xg9, mg9, nullptr, lvl9, wFrag, bias, t * 64, a_lds);
    }
    const float* xg8 = targets + (size_t)255 * B * V;
    const float* mg8 = masks + (size_t)255 * B;
    gru_tile(xg8, mg8, lvl9, lvl8, wFrag, bias, bb * 64, a_lds);
}

// ---------------------------------------------------------------------------
// Pair kernel: levels (du, du-1). Grid = 1<<du blocks. Block bb (i=bb>>1
// lower-node, s=bb&1): 2 du tiles (4i+s, 4i+2+s) then lower tile bb.
// ---------------------------------------------------------------------------
__global__ __launch_bounds__(NTHR, 2) void pair_kernel(
    const float* __restrict__ xg_u, const float* __restrict__ mg_u,
    const float* __restrict__ xg_l, const float* __restrict__ mg_l,
    const unsigned short* __restrict__ prevbuf,
    unsigned short* __restrict__ out_u, unsigned short* __restrict__ out_l,
    const unsigned short* __restrict__ wFrag, const float* __restrict__ bias)
{
    __shared__ __attribute__((aligned(16))) unsigned short a_lds[64 * LDA];

    const int bb = blockIdx.x;
    const int i = bb >> 1;
    const int s = bb & 1;
    #pragma unroll
    for (int q2 = 0; q2 < 2; ++q2) {
        const int t = 2 * (2 * i + q2) + s;
        gru_tile(xg_u, mg_u, prevbuf, out_u, wFrag, bias, t * 64, a_lds);
    }
    gru_tile(xg_l, mg_l, out_u, out_l, wFrag, bias, bb * 64, a_lds);
}

// ---------------------------------------------------------------------------
// Final projection from bf16 root.
// ---------------------------------------------------------------------------
__global__ __launch_bounds__(128) void proj_kernel(
    const unsigned short* __restrict__ root,
    const float* __restrict__ mu_w, const float* __restrict__ mu_b,
    const float* __restrict__ lv_w, const float* __restrict__ lv_b,
    float* __restrict__ out)
{
    __shared__ float r_lds[H];
    int b = blockIdx.x;
    int j = threadIdx.x;
    r_lds[j] = bf2f(root[(size_t)b * H + j]);
    __syncthreads();
    float am = 0.f, al = 0.f;
    #pragma unroll 8
    for (int k = 0; k < H; ++k) {
        float rv = r_lds[k];
        am += rv * mu_w[(size_t)j * H + k];
        al += rv * lv_w[(size_t)j * H + k];
    }
    out[(size_t)b * H + j] = am + mu_b[j];
    out[(size_t)(B * H) + (size_t)b * H + j] = al + lv_b[j];
}

// ---------------------------------------------------------------------------
extern "C" void kernel_launch(void* const* d_in, const int* in_sizes, int n_in,
                              void* d_out, int out_size, void* d_ws, size_t ws_size,
                              hipStream_t stream)
{
    const float* targets = (const float*)d_in[0];
    const float* masks   = (const float*)d_in[1];
    const float* wir_w = (const float*)d_in[2];  const float* wir_b = (const float*)d_in[3];
    const float* whr_w = (const float*)d_in[4];  const float* whr_b = (const float*)d_in[5];
    const float* wiz_w = (const float*)d_in[6];  const float* wiz_b = (const float*)d_in[7];
    const float* whz_w = (const float*)d_in[8];  const float* whz_b = (const float*)d_in[9];
    const float* win_w = (const float*)d_in[10]; const float* win_b = (const float*)d_in[11];
    const float* whn_w = (const float*)d_in[12]; const float* whn_b = (const float*)d_in[13];
    const float* mu_w  = (const float*)d_in[14]; const float* mu_b  = (const float*)d_in[15];
    const float* lv_w  = (const float*)d_in[16]; const float* lv_b  = (const float*)d_in[17];

    // per-level buffers (bf16 elems): lvl[d] size = (1<<d)*B*H
    unsigned short* ws16 = (unsigned short*)d_ws;
    unsigned short* lvl[10];
    size_t off = 0;
    for (int d = 9; d >= 0; --d) { lvl[d] = ws16 + off; off += (size_t)(1 << d) * B * H; }
    unsigned short* wFrag = ws16 + off;                // 9*24*64*8 = 110592 bf16
    float*          biasw = (float*)(wFrag + 110592);  // 4*128 fp32

    prep_pack<<<54, 256, 0, stream>>>(
        wir_w, whr_w, wiz_w, whz_w, win_w, whn_w,
        wir_b, whr_b, wiz_b, whz_b, win_b, whn_b, wFrag, biasw);

    subtree_kernel<<<512, NTHR, 0, stream>>>(targets, masks, lvl[9], lvl[8], wFrag, biasw);

    // tail pairs: (7,6) (5,4) (3,2) (1,0)
    for (int du = 7; du >= 1; du -= 2) {
        int dl = du - 1;
        int su = (1 << du) - 1;
        int sl = (1 << dl) - 1;
        pair_kernel<<<(1 << du), NTHR, 0, stream>>>(
            targets + (size_t)su * B * V, masks + (size_t)su * B,
            targets + (size_t)sl * B * V, masks + (size_t)sl * B,
            lvl[du + 1], lvl[du], lvl[dl], wFrag, biasw);
    }

    proj_kernel<<<128, 128, 0, stream>>>(lvl[0], mu_w, mu_b, lv_w, lv_b, (float*)d_out);
}

// Round 7
// 153.172 us; speedup vs baseline: 3.6839x; 1.0441x over previous
//
#include <hip/hip_runtime.h>
#include <hip/hip_bf16.h>
#include <math.h>

#define B 128
#define V 32
#define H 128
#define LDA 296    // padded A row pitch in bf16 elems (592 B)
#define LDXC 40    // child-x row pitch in bf16 elems (80 B, 16B-aligned)
#define NTHR 512

typedef __attribute__((ext_vector_type(8))) short bf16x8;
typedef __attribute__((ext_vector_type(4))) float f32x4;

__device__ inline f32x4 mfma_bf16(bf16x8 a, bf16x8 b, f32x4 c) {
    return __builtin_amdgcn_mfma_f32_16x16x32_bf16(a, b, c, 0, 0, 0);
}
__device__ inline unsigned short f2bf(float f) {
    __hip_bfloat16 h = __float2bfloat16(f);
    return __builtin_bit_cast(unsigned short, h);
}
__device__ inline float bf2f(unsigned short u) {
    unsigned int x = ((unsigned int)u) << 16;
    return __builtin_bit_cast(float, x);
}
__device__ inline float fast_sigmoid(float x) {
    float e = __builtin_amdgcn_exp2f(x * -1.44269504f);
    return __builtin_amdgcn_rcpf(1.f + e);
}
__device__ inline float fast_tanh(float x) {
    float e = __builtin_amdgcn_exp2f(x * 2.88539008f);   // exp(2x)
    return 1.f - 2.f * __builtin_amdgcn_rcpf(e + 1.f);
}

// ---------------------------------------------------------------------------
// Pack GRU weights + projection weights into MFMA B-fragment order.
// wFrag: (ks*24 + g*8 + t)*64 + lane  (g 0=r,1=z,2=n; t unit-16 tile)
// pFrag: (ks*16 + ct2)*64 + lane      (ct2 = sel*8 + t; sel 0=mu,1=lv; K=128)
// bias: [0]=r, [1]=z, [2]=in, [3]=hn, [4]=mu_b, [5]=lv_b (x128 each)
// ---------------------------------------------------------------------------
__global__ void prep_pack(const float* __restrict__ wir_w, const float* __restrict__ whr_w,
                          const float* __restrict__ wiz_w, const float* __restrict__ whz_w,
                          const float* __restrict__ win_w, const float* __restrict__ whn_w,
                          const float* __restrict__ wir_b, const float* __restrict__ whr_b,
                          const float* __restrict__ wiz_b, const float* __restrict__ whz_b,
                          const float* __restrict__ win_b, const float* __restrict__ whn_b,
                          const float* __restrict__ mu_w, const float* __restrict__ mu_b,
                          const float* __restrict__ lv_w, const float* __restrict__ lv_b,
                          unsigned short* __restrict__ wFrag, unsigned short* __restrict__ pFrag,
                          float* __restrict__ bias)
{
    int idx = blockIdx.x * blockDim.x + threadIdx.x;
    if (idx < 13824) {                       // 9*24*64 GRU frags
        int lane = idx & 63;
        int ctks = idx >> 6;
        int ct = ctks % 24;
        int ks = ctks / 24;
        int g = ct >> 3;
        int t = ct & 7;
        int u = t * 16 + (lane & 15);
        const float* wi = (g == 0) ? wir_w : (g == 1) ? wiz_w : win_w;
        const float* wh = (g == 0) ? whr_w : (g == 1) ? whz_w : whn_w;
        unsigned short v[8] __attribute__((aligned(16)));
        #pragma unroll
        for (int i = 0; i < 8; ++i) {
            float f;
            if (ks == 0) { int k = 8 * (lane >> 4) + i; f = wi[u * V + k]; }
            else         { int k = (ks - 1) * 32 + 8 * (lane >> 4) + i; f = wh[u * 256 + k]; }
            v[i] = f2bf(f);
        }
        *(int4*)(wFrag + (size_t)idx * 8) = *(const int4*)v;
    } else if (idx < 13824 + 4096) {         // 4*16*64 proj frags
        int pidx = idx - 13824;
        int lane = pidx & 63;
        int rest = pidx >> 6;
        int ct2 = rest & 15;
        int ks = rest >> 4;                  // 0..3
        int sel = ct2 >> 3, tl = ct2 & 7;
        int u = tl * 16 + (lane & 15);
        const float* wsrc = sel ? lv_w : mu_w;
        unsigned short v[8] __attribute__((aligned(16)));
        #pragma unroll
        for (int i = 0; i < 8; ++i) {
            int k = ks * 32 + 8 * (lane >> 4) + i;
            v[i] = f2bf(wsrc[u * H + k]);
        }
        *(int4*)(pFrag + (size_t)pidx * 8) = *(const int4*)v;
    }
    if (idx < 6 * H) {
        int s = idx / H, u = idx % H;
        float val;
        if (s == 0)      val = wir_b[u] + whr_b[u];
        else if (s == 1) val = wiz_b[u] + whz_b[u];
        else if (s == 2) val = win_b[u];
        else if (s == 3) val = whn_b[u];
        else if (s == 4) val = mu_b[u];
        else             val = lv_b[u];
        bias[idx] = val;
    }
}

// ---------------------------------------------------------------------------
// One 64-row GRU tile (subtree path). prev==nullptr => h-region pre-filled.
// ---------------------------------------------------------------------------
__device__ __forceinline__ void gru_tile(
    const float* __restrict__ xg, const float* __restrict__ mg,
    const unsigned short* __restrict__ prev, unsigned short* __restrict__ outb,
    const unsigned short* __restrict__ wFrag, const float* __restrict__ bias,
    int Rb, unsigned short* a_lds)
{
    const int tid = threadIdx.x;
    {
        int row = tid >> 3;
        int k4 = (tid & 7) * 4;
        float4 v = *(const float4*)(xg + (size_t)(Rb + row) * V + k4);
        unsigned int lo = (unsigned int)f2bf(v.x) | ((unsigned int)f2bf(v.y) << 16);
        unsigned int hi = (unsigned int)f2bf(v.z) | ((unsigned int)f2bf(v.w) << 16);
        uint2 p; p.x = lo; p.y = hi;
        *(uint2*)(&a_lds[row * LDA + k4]) = p;
    }
    if (prev) {
        const int node = Rb >> 7;
        const int b0 = Rb & 127;
        const unsigned short* pl = prev + ((size_t)(2 * node) * B + b0) * H;
        const unsigned short* pr = prev + ((size_t)(2 * node + 1) * B + b0) * H;
        #pragma unroll
        for (int c = 0; c < 4; ++c) {
            int f = c * NTHR + tid;
            int row = f >> 5;
            int chunk = f & 31;
            const unsigned short* src = (chunk < 16) ? (pl + row * H + chunk * 8)
                                                     : (pr + row * H + (chunk - 16) * 8);
            int4 v = *(const int4*)src;
            *(int4*)(&a_lds[row * LDA + 32 + chunk * 8]) = v;
        }
    }
    __syncthreads();

    const int lane = tid & 63;
    const int w = tid >> 6;
    const int wc = w & 3;
    const int rbase = (w >> 2) * 32;
    const int l15 = lane & 15;
    const int lg = lane >> 4;

    f32x4 zero4 = {0.f, 0.f, 0.f, 0.f};
    f32x4 acc_r[2][2], acc_z[2][2], acc_in[2][2], acc_hn[2][2];
    #pragma unroll
    for (int a = 0; a < 2; ++a)
        #pragma unroll
        for (int b = 0; b < 2; ++b) {
            acc_r[a][b] = zero4; acc_z[a][b] = zero4;
            acc_in[a][b] = zero4; acc_hn[a][b] = zero4;
        }

    {
        bf16x8 a0 = *(const bf16x8*)(&a_lds[(rbase + l15) * LDA + 8 * lg]);
        bf16x8 a1 = *(const bf16x8*)(&a_lds[(rbase + 16 + l15) * LDA + 8 * lg]);
        #pragma unroll
        for (int t = 0; t < 2; ++t) {
            int tt = 2 * wc + t;
            bf16x8 br_ = *(const bf16x8*)(wFrag + ((size_t)(tt) * 64 + lane) * 8);
            bf16x8 bz_ = *(const bf16x8*)(wFrag + ((size_t)(8 + tt) * 64 + lane) * 8);
            bf16x8 bn_ = *(const bf16x8*)(wFrag + ((size_t)(16 + tt) * 64 + lane) * 8);
            acc_r[0][t] = mfma_bf16(a0, br_, acc_r[0][t]);
            acc_r[1][t] = mfma_bf16(a1, br_, acc_r[1][t]);
            acc_z[0][t] = mfma_bf16(a0, bz_, acc_z[0][t]);
            acc_z[1][t] = mfma_bf16(a1, bz_, acc_z[1][t]);
            acc_in[0][t] = mfma_bf16(a0, bn_, acc_in[0][t]);
            acc_in[1][t] = mfma_bf16(a1, bn_, acc_in[1][t]);
        }
    }
    #pragma unroll 2
    for (int ks = 1; ks <= 8; ++ks) {
        bf16x8 a0 = *(const bf16x8*)(&a_lds[(rbase + l15) * LDA + ks * 32 + 8 * lg]);
        bf16x8 a1 = *(const bf16x8*)(&a_lds[(rbase + 16 + l15) * LDA + ks * 32 + 8 * lg]);
        size_t fb = (size_t)ks * 24 * 64;
        #pragma unroll
        for (int t = 0; t < 2; ++t) {
            int tt = 2 * wc + t;
            bf16x8 br_ = *(const bf16x8*)(wFrag + (fb + (size_t)(tt) * 64 + lane) * 8);
            bf16x8 bz_ = *(const bf16x8*)(wFrag + (fb + (size_t)(8 + tt) * 64 + lane) * 8);
            bf16x8 bn_ = *(const bf16x8*)(wFrag + (fb + (size_t)(16 + tt) * 64 + lane) * 8);
            acc_r[0][t] = mfma_bf16(a0, br_, acc_r[0][t]);
            acc_r[1][t] = mfma_bf16(a1, br_, acc_r[1][t]);
            acc_z[0][t] = mfma_bf16(a0, bz_, acc_z[0][t]);
            acc_z[1][t] = mfma_bf16(a1, bz_, acc_z[1][t]);
            acc_hn[0][t] = mfma_bf16(a0, bn_, acc_hn[0][t]);
            acc_hn[1][t] = mfma_bf16(a1, bn_, acc_hn[1][t]);
        }
    }

    #pragma unroll
    for (int t = 0; t < 2; ++t) {
        int u = wc * 32 + t * 16 + l15;
        float br = bias[u];
        float bz = bias[128 + u];
        float bin = bias[256 + u];
        float bhn = bias[384 + u];
        #pragma unroll
        for (int rt = 0; rt < 2; ++rt) {
            float4 mv = *(const float4*)(mg + Rb + rbase + rt * 16 + lg * 4);
            const float* mp = (const float*)&mv;
            #pragma unroll
            for (int reg = 0; reg < 4; ++reg) {
                int row = rbase + rt * 16 + lg * 4 + reg;
                float ar = acc_r[rt][t][reg] + br;
                float az = acc_z[rt][t][reg] + bz;
                float ain = acc_in[rt][t][reg] + bin;
                float ahn = acc_hn[rt][t][reg] + bhn;
                float rg = fast_sigmoid(ar);
                float zg = fast_sigmoid(az);
                float cg = fast_tanh(ain + rg * ahn);
                float h1 = bf2f(a_lds[row * LDA + 32 + u]);
                float h2 = bf2f(a_lds[row * LDA + 160 + u]);
                float ho = (1.f - zg) * cg + zg * 0.5f * (h1 + h2);
                outb[(size_t)(Rb + row) * H + u] = f2bf(ho * mp[reg]);
            }
        }
    }
    __syncthreads();
}

// ---------------------------------------------------------------------------
// Leaf pair -> a_lds h-region (subtree path).
// ---------------------------------------------------------------------------
__device__ __forceinline__ void leaf_pair(
    const float* __restrict__ targets, const float* __restrict__ masks,
    const unsigned short* __restrict__ wFrag, const float* __restrict__ bias,
    int j, int b0, unsigned short* a_lds, unsigned short* xc_lds)
{
    const int tid = threadIdx.x;
    const int lane = tid & 63;
    const int w = tid >> 6;
    const int l15 = lane & 15;
    const int lg = lane >> 4;
    const size_t lbase = (size_t)(1023 + 2 * j) * B;

    #pragma unroll
    for (int c2 = 0; c2 < 2; ++c2) {
        int task = c2 * NTHR + tid;
        int row = task >> 3;
        int chunk = task & 7;
        int child = row >> 6;
        int rowl = row & 63;
        float4 v = *(const float4*)(targets + (lbase + (size_t)child * B + b0 + rowl) * V + chunk * 4);
        unsigned int lo = (unsigned int)f2bf(v.x) | ((unsigned int)f2bf(v.y) << 16);
        unsigned int hi = (unsigned int)f2bf(v.z) | ((unsigned int)f2bf(v.w) << 16);
        uint2 p; p.x = lo; p.y = hi;
        *(uint2*)(&xc_lds[row * LDXC + chunk * 4]) = p;
    }
    __syncthreads();
    const int c = w >> 2;
    const int q = w & 3;
    bf16x8 af = *(const bf16x8*)(&xc_lds[(c * 64 + q * 16 + l15) * LDXC + 8 * lg]);
    float4 mv = *(const float4*)(masks + lbase + (size_t)c * B + b0 + q * 16 + lg * 4);
    const float* mp = (const float*)&mv;
    #pragma unroll
    for (int pass = 0; pass < 2; ++pass) {
        f32x4 ar[4], az[4], an[4];
        #pragma unroll
        for (int t2 = 0; t2 < 4; ++t2) {
            int tt = pass * 4 + t2;
            bf16x8 br_ = *(const bf16x8*)(wFrag + ((size_t)(tt) * 64 + lane) * 8);
            bf16x8 bz_ = *(const bf16x8*)(wFrag + ((size_t)(8 + tt) * 64 + lane) * 8);
            bf16x8 bn_ = *(const bf16x8*)(wFrag + ((size_t)(16 + tt) * 64 + lane) * 8);
            f32x4 z4 = {0.f, 0.f, 0.f, 0.f};
            ar[t2] = mfma_bf16(af, br_, z4);
            az[t2] = mfma_bf16(af, bz_, z4);
            an[t2] = mfma_bf16(af, bn_, z4);
        }
        #pragma unroll
        for (int t2 = 0; t2 < 4; ++t2) {
            int u = (pass * 4 + t2) * 16 + l15;
            float br = bias[u];
            float bz = bias[128 + u];
            float bin = bias[256 + u];
            float bhn = bias[384 + u];
            #pragma unroll
            for (int reg = 0; reg < 4; ++reg) {
                int rowl = q * 16 + lg * 4 + reg;
                float rg = fast_sigmoid(ar[t2][reg] + br);
                float zg = fast_sigmoid(az[t2][reg] + bz);
                float cg = fast_tanh(an[t2][reg] + bin + rg * bhn);
                float ho = (1.f - zg) * cg;
                a_lds[rowl * LDA + 32 + c * 128 + u] = f2bf(ho * mp[reg]);
            }
        }
    }
}

// ---------------------------------------------------------------------------
// Subtree kernel (levels leaf,9,8): grid 512, unchanged from R6.
// ---------------------------------------------------------------------------
__global__ __launch_bounds__(NTHR, 2) void subtree_kernel(
    const float* __restrict__ targets, const float* __restrict__ masks,
    unsigned short* __restrict__ lvl9, unsigned short* __restrict__ lvl8,
    const unsigned short* __restrict__ wFrag, const float* __restrict__ bias)
{
    __shared__ __attribute__((aligned(16))) unsigned short a_lds[64 * LDA];
    __shared__ __attribute__((aligned(16))) unsigned short xc_lds[128 * LDXC];

    const int bb = blockIdx.x;
    const int i = bb >> 1;
    const int s = bb & 1;

    const float* xg9 = targets + (size_t)511 * B * V;
    const float* mg9 = masks + (size_t)511 * B;
    #pragma unroll
    for (int q2 = 0; q2 < 2; ++q2) {
        const int j = 2 * i + q2;
        const int t = 2 * j + s;
        leaf_pair(targets, masks, wFrag, bias, j, s * 64, a_lds, xc_lds);
        gru_tile(xg9, mg9, nullptr, lvl9, wFrag, bias, t * 64, a_lds);
    }
    const float* xg8 = targets + (size_t)255 * B * V;
    const float* mg8 = masks + (size_t)255 * B;
    gru_tile(xg8, mg8, lvl9, lvl8, wFrag, bias, bb * 64, a_lds);
}

// ---------------------------------------------------------------------------
// Tail kernel: 4 levels d_top..d_top-3 of one subtree x one 16-row batch
// chunk per block. 15 serial M=16 tiles; weights-stationary (27 B-frags in
// VGPRs per wave); x/h staging prefetched into regs one tile ahead (T14).
// Block bb: n = bb>>3 (subtree root at level d_top-3), c = bb&7 (chunk).
// Optional fused projection (do_proj): root h -> mu/logvar into d_out.
// ---------------------------------------------------------------------------
__global__ __launch_bounds__(NTHR) void tail_kernel(
    const float* __restrict__ targets, const float* __restrict__ masks,
    const unsigned short* __restrict__ prevTop,
    unsigned short* __restrict__ o0, unsigned short* __restrict__ o1,
    unsigned short* __restrict__ o2, unsigned short* __restrict__ o3,
    int d_top,
    const unsigned short* __restrict__ wFrag, const float* __restrict__ bias,
    int do_proj, const unsigned short* __restrict__ pFrag, float* __restrict__ proj_out)
{
    __shared__ __attribute__((aligned(16))) unsigned short a16[16 * LDA];  // 9472 B

    const int tid = threadIdx.x;
    const int lane = tid & 63;
    const int w = tid >> 6;
    const int l15 = lane & 15;
    const int lg = lane >> 4;
    const int n = blockIdx.x >> 3;
    const int c = blockIdx.x & 7;
    const int droot = d_top - 3;

    // weights-stationary: 27 B-frags (this wave's 16-unit group) in VGPRs
    bf16x8 wreg[9][3];
    #pragma unroll
    for (int ks = 0; ks < 9; ++ks)
        #pragma unroll
        for (int g = 0; g < 3; ++g)
            wreg[ks][g] = *(const bf16x8*)(wFrag + (((size_t)ks * 24 + g * 8 + w) * 64 + lane) * 8);

    auto decode = [&](int t, int& d, int& ld) {
        int k;
        if (t < 8)       { d = d_top;     k = t; }
        else if (t < 12) { d = d_top - 1; k = t - 8; }
        else if (t < 14) { d = d_top - 2; k = t - 12; }
        else             { d = d_top - 3; k = 0; }
        ld = (n << (d - droot)) + k;
    };
    auto childbuf = [&](int d) -> const unsigned short* {
        if (d == d_top)     return prevTop;
        if (d == d_top - 1) return o0;
        if (d == d_top - 2) return o1;
        return o2;
    };
    auto outbuf = [&](int d) -> unsigned short* {
        if (d == d_top)     return o0;
        if (d == d_top - 1) return o1;
        if (d == d_top - 2) return o2;
        return o3;
    };

    float4 xreg;
    int4 hreg;
    auto load_x = [&](int d, int ld) {
        if (tid < 128) {
            int row = tid >> 3, chunk = tid & 7;
            size_t gnode = (size_t)((1 << d) - 1) + ld;
            xreg = *(const float4*)(targets + (gnode * B + (size_t)c * 16 + row) * V + chunk * 4);
        }
    };
    auto load_h = [&](int d, int ld) {
        const unsigned short* cb = childbuf(d);
        int row = tid >> 5, chunk = tid & 31;
        int which = chunk >> 4, ck = chunk & 15;
        hreg = *(const int4*)(cb + (((size_t)(2 * ld + which)) * B + (size_t)c * 16 + row) * H + ck * 8);
    };

    int dcur, ldcur;
    decode(0, dcur, ldcur);
    load_x(dcur, ldcur);
    load_h(dcur, ldcur);
    bool have_h = true;

    for (int t = 0; t < 15; ++t) {
        decode(t, dcur, ldcur);
        if (!have_h) load_h(dcur, ldcur);   // root tile: children synced last iter
        // write staged regs -> LDS
        if (tid < 128) {
            int row = tid >> 3, k4 = (tid & 7) * 4;
            unsigned int lo = (unsigned int)f2bf(xreg.x) | ((unsigned int)f2bf(xreg.y) << 16);
            unsigned int hi = (unsigned int)f2bf(xreg.z) | ((unsigned int)f2bf(xreg.w) << 16);
            uint2 p; p.x = lo; p.y = hi;
            *(uint2*)(&a16[row * LDA + k4]) = p;
        }
        {
            int row = tid >> 5, chunk = tid & 31;
            *(int4*)(&a16[row * LDA + 32 + chunk * 8]) = hreg;
        }
        __syncthreads();
        // prefetch next tile (x always; h unless next tile's child is this one)
        if (t + 1 < 15) {
            int dn, ldn;
            decode(t + 1, dn, ldn);
            load_x(dn, ldn);
            if (t != 13) { load_h(dn, ldn); have_h = true; }
            else have_h = false;
        }
        // compute: M=16, all 9 K-steps, weights from registers
        f32x4 acc_r = {0.f, 0.f, 0.f, 0.f};
        f32x4 acc_z = acc_r, acc_in = acc_r, acc_hn = acc_r;
        #pragma unroll
        for (int ks = 0; ks < 9; ++ks) {
            bf16x8 a = *(const bf16x8*)(&a16[l15 * LDA + ks * 32 + 8 * lg]);
            acc_r = mfma_bf16(a, wreg[ks][0], acc_r);
            acc_z = mfma_bf16(a, wreg[ks][1], acc_z);
            if (ks == 0) acc_in = mfma_bf16(a, wreg[0][2], acc_in);
            else         acc_hn = mfma_bf16(a, wreg[ks][2], acc_hn);
        }
        // epilogue
        {
            int u = w * 16 + l15;
            float br = bias[u];
            float bz = bias[128 + u];
            float bin = bias[256 + u];
            float bhn = bias[384 + u];
            size_t gnode = (size_t)((1 << dcur) - 1) + ldcur;
            const float* mrow = masks + gnode * B + (size_t)c * 16;
            unsigned short* orow = outbuf(dcur) + ((size_t)ldcur * B + (size_t)c * 16) * H;
            #pragma unroll
            for (int reg = 0; reg < 4; ++reg) {
                int row = lg * 4 + reg;
                float m = mrow[row];
                float ar = acc_r[reg] + br;
                float az = acc_z[reg] + bz;
                float ain = acc_in[reg] + bin;
                float ahn = acc_hn[reg] + bhn;
                float rg = fast_sigmoid(ar);
                float zg = fast_sigmoid(az);
                float cg = fast_tanh(ain + rg * ahn);
                float h1 = bf2f(a16[row * LDA + 32 + u]);
                float h2 = bf2f(a16[row * LDA + 160 + u]);
                float ho = (1.f - zg) * cg + zg * 0.5f * (h1 + h2);
                unsigned short hb = f2bf(ho * m);
                orow[(size_t)row * H + u] = hb;
                if (do_proj && t == 14) a16[row * LDA + 32 + u] = hb;  // root h for proj
            }
        }
        __syncthreads();
    }

    if (do_proj) {
        // mu = h @ mu_w.T + mu_b ; lv = h @ lv_w.T + lv_b  (M=16, K=128, N=256)
        f32x4 p0 = {0.f, 0.f, 0.f, 0.f}, p1 = p0;
        #pragma unroll
        for (int ks = 0; ks < 4; ++ks) {
            bf16x8 a = *(const bf16x8*)(&a16[l15 * LDA + 32 + ks * 32 + 8 * lg]);
            bf16x8 f0 = *(const bf16x8*)(pFrag + (((size_t)ks * 16 + 2 * w) * 64 + lane) * 8);
            bf16x8 f1 = *(const bf16x8*)(pFrag + (((size_t)ks * 16 + 2 * w + 1) * 64 + lane) * 8);
            p0 = mfma_bf16(a, f0, p0);
            p1 = mfma_bf16(a, f1, p1);
        }
        #pragma unroll
        for (int j = 0; j < 2; ++j) {
            int ct2 = 2 * w + j;
            int sel = ct2 >> 3, tl = ct2 & 7;
            int u = tl * 16 + l15;
            float bb = bias[512 + sel * 128 + u];
            f32x4 pv = j ? p1 : p0;
            #pragma unroll
            for (int reg = 0; reg < 4; ++reg) {
                int row = c * 16 + lg * 4 + reg;
                proj_out[((size_t)sel * B + row) * H + u] = pv[reg] + bb;
            }
        }
    }
}

// ---------------------------------------------------------------------------
extern "C" void kernel_launch(void* const* d_in, const int* in_sizes, int n_in,
                              void* d_out, int out_size, void* d_ws, size_t ws_size,
                              hipStream_t stream)
{
    const float* targets = (const float*)d_in[0];
    const float* masks   = (const float*)d_in[1];
    const float* wir_w = (const float*)d_in[2];  const float* wir_b = (const float*)d_in[3];
    const float* whr_w = (const float*)d_in[4];  const float* whr_b = (const float*)d_in[5];
    const float* wiz_w = (const float*)d_in[6];  const float* wiz_b = (const float*)d_in[7];
    const float* whz_w = (const float*)d_in[8];  const float* whz_b = (const float*)d_in[9];
    const float* win_w = (const float*)d_in[10]; const float* win_b = (const float*)d_in[11];
    const float* whn_w = (const float*)d_in[12]; const float* whn_b = (const float*)d_in[13];
    const float* mu_w  = (const float*)d_in[14]; const float* mu_b  = (const float*)d_in[15];
    const float* lv_w  = (const float*)d_in[16]; const float* lv_b  = (const float*)d_in[17];

    // per-level buffers (bf16): lvl[d] = (1<<d)*B*H
    unsigned short* ws16 = (unsigned short*)d_ws;
    unsigned short* lvl[10];
    size_t off = 0;
    for (int d = 9; d >= 0; --d) { lvl[d] = ws16 + off; off += (size_t)(1 << d) * B * H; }
    unsigned short* wFrag = ws16 + off;               // 110592 bf16
    unsigned short* pFrag = wFrag + 110592;           // 32768 bf16
    float*          biasw = (float*)(pFrag + 32768);  // 768 fp32

    prep_pack<<<70, 256, 0, stream>>>(
        wir_w, whr_w, wiz_w, whz_w, win_w, whn_w,
        wir_b, whr_b, wiz_b, whz_b, win_b, whn_b,
        mu_w, mu_b, lv_w, lv_b, wFrag, pFrag, biasw);

    subtree_kernel<<<512, NTHR, 0, stream>>>(targets, masks, lvl[9], lvl[8], wFrag, biasw);

    // tail1: levels 7..4, one d4-subtree x 16-row chunk per block
    tail_kernel<<<128, NTHR, 0, stream>>>(
        targets, masks, lvl[8], lvl[7], lvl[6], lvl[5], lvl[4],
        7, wFrag, biasw, 0, nullptr, nullptr);

    // tail2: levels 3..0 + fused projection
    tail_kernel<<<8, NTHR, 0, stream>>>(
        targets, masks, lvl[4], lvl[3], lvl[2], lvl[1], lvl[0],
        3, wFrag, biasw, 1, pFrag, (float*)d_out);
}

// Round 8
// 131.550 us; speedup vs baseline: 4.2894x; 1.1644x over previous
//
#include <hip/hip_runtime.h>
#include <hip/hip_bf16.h>
#include <math.h>

#define B 128
#define V 32
#define H 128
#define LDH 264    // h-region row pitch in bf16 elems (528 B)
#define NTHR 256

typedef __attribute__((ext_vector_type(8))) short bf16x8;
typedef __attribute__((ext_vector_type(4))) float f32x4;

__device__ inline f32x4 mfma_bf16(bf16x8 a, bf16x8 b, f32x4 c) {
    return __builtin_amdgcn_mfma_f32_16x16x32_bf16(a, b, c, 0, 0, 0);
}
__device__ inline unsigned short f2bf(float f) {
    __hip_bfloat16 h = __float2bfloat16(f);
    return __builtin_bit_cast(unsigned short, h);
}
__device__ inline float bf2f(unsigned short u) {
    unsigned int x = ((unsigned int)u) << 16;
    return __builtin_bit_cast(float, x);
}
__device__ inline float fast_sigmoid(float x) {
    float e = __builtin_amdgcn_exp2f(x * -1.44269504f);
    return __builtin_amdgcn_rcpf(1.f + e);
}
__device__ inline float fast_tanh(float x) {
    float e = __builtin_amdgcn_exp2f(x * 2.88539008f);   // exp(2x)
    return 1.f - 2.f * __builtin_amdgcn_rcpf(e + 1.f);
}
// build bf16x8 A-fragment from 8 consecutive fp32 (32B contiguous per lane)
__device__ inline bf16x8 load_xfrag(const float* p) {
    float4 a = *(const float4*)p;
    float4 b = *(const float4*)(p + 4);
    bf16x8 r;
    r[0] = (short)f2bf(a.x); r[1] = (short)f2bf(a.y);
    r[2] = (short)f2bf(a.z); r[3] = (short)f2bf(a.w);
    r[4] = (short)f2bf(b.x); r[5] = (short)f2bf(b.y);
    r[6] = (short)f2bf(b.z); r[7] = (short)f2bf(b.w);
    return r;
}

// ---------------------------------------------------------------------------
// Pack GRU weights + projection weights into MFMA B-fragment order.
// wFrag: (ks*24 + g*8 + t)*64 + lane  (g 0=r,1=z,2=n; t unit-16 tile)
// pFrag: (ks*16 + ct2)*64 + lane      (ct2 = sel*8 + t; sel 0=mu,1=lv; K=128)
// bias: [0]=r, [1]=z, [2]=in, [3]=hn, [4]=mu_b, [5]=lv_b (x128 each)
// ---------------------------------------------------------------------------
__global__ void prep_pack(const float* __restrict__ wir_w, const float* __restrict__ whr_w,
                          const float* __restrict__ wiz_w, const float* __restrict__ whz_w,
                          const float* __restrict__ win_w, const float* __restrict__ whn_w,
                          const float* __restrict__ wir_b, const float* __restrict__ whr_b,
                          const float* __restrict__ wiz_b, const float* __restrict__ whz_b,
                          const float* __restrict__ win_b, const float* __restrict__ whn_b,
                          const float* __restrict__ mu_w, const float* __restrict__ mu_b,
                          const float* __restrict__ lv_w, const float* __restrict__ lv_b,
                          unsigned short* __restrict__ wFrag, unsigned short* __restrict__ pFrag,
                          float* __restrict__ bias)
{
    int idx = blockIdx.x * blockDim.x + threadIdx.x;
    if (idx < 13824) {                       // 9*24*64 GRU frags
        int lane = idx & 63;
        int ctks = idx >> 6;
        int ct = ctks % 24;
        int ks = ctks / 24;
        int g = ct >> 3;
        int t = ct & 7;
        int u = t * 16 + (lane & 15);
        const float* wi = (g == 0) ? wir_w : (g == 1) ? wiz_w : win_w;
        const float* wh = (g == 0) ? whr_w : (g == 1) ? whz_w : whn_w;
        unsigned short v[8] __attribute__((aligned(16)));
        #pragma unroll
        for (int i = 0; i < 8; ++i) {
            float f;
            if (ks == 0) { int k = 8 * (lane >> 4) + i; f = wi[u * V + k]; }
            else         { int k = (ks - 1) * 32 + 8 * (lane >> 4) + i; f = wh[u * 256 + k]; }
            v[i] = f2bf(f);
        }
        *(int4*)(wFrag + (size_t)idx * 8) = *(const int4*)v;
    } else if (idx < 13824 + 4096) {         // 4*16*64 proj frags
        int pidx = idx - 13824;
        int lane = pidx & 63;
        int rest = pidx >> 6;
        int ct2 = rest & 15;
        int ks = rest >> 4;                  // 0..3
        int sel = ct2 >> 3, tl = ct2 & 7;
        int u = tl * 16 + (lane & 15);
        const float* wsrc = sel ? lv_w : mu_w;
        unsigned short v[8] __attribute__((aligned(16)));
        #pragma unroll
        for (int i = 0; i < 8; ++i) {
            int k = ks * 32 + 8 * (lane >> 4) + i;
            v[i] = f2bf(wsrc[u * H + k]);
        }
        *(int4*)(pFrag + (size_t)pidx * 8) = *(const int4*)v;
    }
    if (idx < 6 * H) {
        int s = idx / H, u = idx % H;
        float val;
        if (s == 0)      val = wir_b[u] + whr_b[u];
        else if (s == 1) val = wiz_b[u] + whz_b[u];
        else if (s == 2) val = win_b[u];
        else if (s == 3) val = whn_b[u];
        else if (s == 4) val = mu_b[u];
        else             val = lv_b[u];
        bias[idx] = val;
    }
}

// ---------------------------------------------------------------------------
// Kernel A: leaf + d9. Grid 2048: block (j = bid>>2 d9 node, q = bid&3
// 32-row batch chunk). 4 waves; wave w owns units [w*32, w*32+32).
// Leaf x and d9 x come straight from global into A-fragment registers.
// ONE barrier per block. LDS = h-region only (32 x 264 bf16).
// ---------------------------------------------------------------------------
__global__ __launch_bounds__(NTHR, 4) void leaf_d9_kernel(
    const float* __restrict__ targets, const float* __restrict__ masks,
    unsigned short* __restrict__ lvl9,
    const unsigned short* __restrict__ wFrag, const float* __restrict__ bias)
{
    __shared__ __attribute__((aligned(16))) unsigned short h_lds[32 * LDH]; // 16896 B

    const int tid = threadIdx.x;
    const int lane = tid & 63;
    const int w = tid >> 6;
    const int l15 = lane & 15;
    const int lg = lane >> 4;
    const int j = blockIdx.x >> 2;
    const int q = blockIdx.x & 3;

    // prefetch d9 x fragments (consumed after the barrier)
    const size_t r9 = (size_t)(511 + j) * B + (size_t)q * 32;
    bf16x8 x9_0 = load_xfrag(targets + (r9 + l15) * V + 8 * lg);
    bf16x8 x9_1 = load_xfrag(targets + (r9 + 16 + l15) * V + 8 * lg);

    // ---- leaf children -> h_lds ----
    #pragma unroll
    for (int c = 0; c < 2; ++c) {
        const size_t crow = (size_t)(1023 + 2 * j + c) * B + (size_t)q * 32;
        bf16x8 xf0 = load_xfrag(targets + (crow + l15) * V + 8 * lg);
        bf16x8 xf1 = load_xfrag(targets + (crow + 16 + l15) * V + 8 * lg);
        f32x4 z4 = {0.f, 0.f, 0.f, 0.f};
        f32x4 ar[2][2], az[2][2], an[2][2];
        #pragma unroll
        for (int rt = 0; rt < 2; ++rt)
            #pragma unroll
            for (int t = 0; t < 2; ++t) { ar[rt][t] = z4; az[rt][t] = z4; an[rt][t] = z4; }
        #pragma unroll
        for (int t = 0; t < 2; ++t) {
            int tt = 2 * w + t;
            bf16x8 br_ = *(const bf16x8*)(wFrag + ((size_t)(tt) * 64 + lane) * 8);
            bf16x8 bz_ = *(const bf16x8*)(wFrag + ((size_t)(8 + tt) * 64 + lane) * 8);
            bf16x8 bn_ = *(const bf16x8*)(wFrag + ((size_t)(16 + tt) * 64 + lane) * 8);
            ar[0][t] = mfma_bf16(xf0, br_, ar[0][t]);
            ar[1][t] = mfma_bf16(xf1, br_, ar[1][t]);
            az[0][t] = mfma_bf16(xf0, bz_, az[0][t]);
            az[1][t] = mfma_bf16(xf1, bz_, az[1][t]);
            an[0][t] = mfma_bf16(xf0, bn_, an[0][t]);
            an[1][t] = mfma_bf16(xf1, bn_, an[1][t]);
        }
        #pragma unroll
        for (int t = 0; t < 2; ++t) {
            int u = w * 32 + t * 16 + l15;
            float br = bias[u], bz = bias[128 + u], bin = bias[256 + u], bhn = bias[384 + u];
            #pragma unroll
            for (int rt = 0; rt < 2; ++rt) {
                float4 mv = *(const float4*)(masks + crow + rt * 16 + lg * 4);
                const float* mp = (const float*)&mv;
                #pragma unroll
                for (int reg = 0; reg < 4; ++reg) {
                    int row = rt * 16 + lg * 4 + reg;
                    float rg = fast_sigmoid(ar[rt][t][reg] + br);
                    float zg = fast_sigmoid(az[rt][t][reg] + bz);
                    float cg = fast_tanh(an[rt][t][reg] + bin + rg * bhn);
                    float ho = (1.f - zg) * cg;
                    h_lds[row * LDH + c * 128 + u] = f2bf(ho * mp[reg]);
                }
            }
        }
    }
    __syncthreads();

    // ---- d9 tile: K0 from x9 regs, K1..8 from h_lds ----
    f32x4 z4 = {0.f, 0.f, 0.f, 0.f};
    f32x4 acc_r[2][2], acc_z[2][2], acc_in[2][2], acc_hn[2][2];
    #pragma unroll
    for (int rt = 0; rt < 2; ++rt)
        #pragma unroll
        for (int t = 0; t < 2; ++t) {
            acc_r[rt][t] = z4; acc_z[rt][t] = z4; acc_in[rt][t] = z4; acc_hn[rt][t] = z4;
        }
    #pragma unroll
    for (int t = 0; t < 2; ++t) {
        int tt = 2 * w + t;
        bf16x8 br_ = *(const bf16x8*)(wFrag + ((size_t)(tt) * 64 + lane) * 8);
        bf16x8 bz_ = *(const bf16x8*)(wFrag + ((size_t)(8 + tt) * 64 + lane) * 8);
        bf16x8 bn_ = *(const bf16x8*)(wFrag + ((size_t)(16 + tt) * 64 + lane) * 8);
        acc_r[0][t] = mfma_bf16(x9_0, br_, acc_r[0][t]);
        acc_r[1][t] = mfma_bf16(x9_1, br_, acc_r[1][t]);
        acc_z[0][t] = mfma_bf16(x9_0, bz_, acc_z[0][t]);
        acc_z[1][t] = mfma_bf16(x9_1, bz_, acc_z[1][t]);
        acc_in[0][t] = mfma_bf16(x9_0, bn_, acc_in[0][t]);
        acc_in[1][t] = mfma_bf16(x9_1, bn_, acc_in[1][t]);
    }
    #pragma unroll 2
    for (int ks = 1; ks <= 8; ++ks) {
        bf16x8 a0 = *(const bf16x8*)(&h_lds[l15 * LDH + (ks - 1) * 32 + 8 * lg]);
        bf16x8 a1 = *(const bf16x8*)(&h_lds[(16 + l15) * LDH + (ks - 1) * 32 + 8 * lg]);
        size_t fb = (size_t)ks * 24 * 64;
        #pragma unroll
        for (int t = 0; t < 2; ++t) {
            int tt = 2 * w + t;
            bf16x8 br_ = *(const bf16x8*)(wFrag + (fb + (size_t)(tt) * 64 + lane) * 8);
            bf16x8 bz_ = *(const bf16x8*)(wFrag + (fb + (size_t)(8 + tt) * 64 + lane) * 8);
            bf16x8 bn_ = *(const bf16x8*)(wFrag + (fb + (size_t)(16 + tt) * 64 + lane) * 8);
            acc_r[0][t] = mfma_bf16(a0, br_, acc_r[0][t]);
            acc_r[1][t] = mfma_bf16(a1, br_, acc_r[1][t]);
            acc_z[0][t] = mfma_bf16(a0, bz_, acc_z[0][t]);
            acc_z[1][t] = mfma_bf16(a1, bz_, acc_z[1][t]);
            acc_hn[0][t] = mfma_bf16(a0, bn_, acc_hn[0][t]);
            acc_hn[1][t] = mfma_bf16(a1, bn_, acc_hn[1][t]);
        }
    }
    #pragma unroll
    for (int t = 0; t < 2; ++t) {
        int u = w * 32 + t * 16 + l15;
        float br = bias[u], bz = bias[128 + u], bin = bias[256 + u], bhn = bias[384 + u];
        #pragma unroll
        for (int rt = 0; rt < 2; ++rt) {
            float4 mv = *(const float4*)(masks + r9 + rt * 16 + lg * 4);
            const float* mp = (const float*)&mv;
            #pragma unroll
            for (int reg = 0; reg < 4; ++reg) {
                int row = rt * 16 + lg * 4 + reg;
                float rg = fast_sigmoid(acc_r[rt][t][reg] + br);
                float zg = fast_sigmoid(acc_z[rt][t][reg] + bz);
                float cg = fast_tanh(acc_in[rt][t][reg] + bin + rg * (acc_hn[rt][t][reg] + bhn));
                float h1 = bf2f(h_lds[row * LDH + u]);
                float h2 = bf2f(h_lds[row * LDH + 128 + u]);
                float ho = (1.f - zg) * cg + zg * 0.5f * (h1 + h2);
                lvl9[((size_t)j * B + (size_t)q * 32 + row) * H + u] = f2bf(ho * mp[reg]);
            }
        }
    }
}

// ---------------------------------------------------------------------------
// Kernel B: one full level (used for d8). Grid = nodes*4: block (n, q-chunk).
// h staged from prev level's global buffer; x from registers; one barrier.
// ---------------------------------------------------------------------------
__global__ __launch_bounds__(NTHR, 4) void level_kernel(
    const float* __restrict__ targets, const float* __restrict__ masks,
    int start,                         // (1<<d)-1
    const unsigned short* __restrict__ prev, unsigned short* __restrict__ outb,
    const unsigned short* __restrict__ wFrag, const float* __restrict__ bias)
{
    __shared__ __attribute__((aligned(16))) unsigned short h_lds[32 * LDH];

    const int tid = threadIdx.x;
    const int lane = tid & 63;
    const int w = tid >> 6;
    const int l15 = lane & 15;
    const int lg = lane >> 4;
    const int n = blockIdx.x >> 2;
    const int q = blockIdx.x & 3;

    // stage h = [h(2n) | h(2n+1)] rows q*32..+32
    #pragma unroll
    for (int t = 0; t < 4; ++t) {
        int task = t * NTHR + tid;          // 1024 chunks of 8 bf16
        int row = task >> 5;
        int ck = task & 31;
        int4 v = *(const int4*)(prev + (((size_t)(2 * n + (ck >> 4))) * B + (size_t)q * 32 + row) * H + (ck & 15) * 8);
        *(int4*)(&h_lds[row * LDH + ck * 8]) = v;
    }
    const size_t rx = (size_t)(start + n) * B + (size_t)q * 32;
    bf16x8 x0 = load_xfrag(targets + (rx + l15) * V + 8 * lg);
    bf16x8 x1 = load_xfrag(targets + (rx + 16 + l15) * V + 8 * lg);
    __syncthreads();

    f32x4 z4 = {0.f, 0.f, 0.f, 0.f};
    f32x4 acc_r[2][2], acc_z[2][2], acc_in[2][2], acc_hn[2][2];
    #pragma unroll
    for (int rt = 0; rt < 2; ++rt)
        #pragma unroll
        for (int t = 0; t < 2; ++t) {
            acc_r[rt][t] = z4; acc_z[rt][t] = z4; acc_in[rt][t] = z4; acc_hn[rt][t] = z4;
        }
    #pragma unroll
    for (int t = 0; t < 2; ++t) {
        int tt = 2 * w + t;
        bf16x8 br_ = *(const bf16x8*)(wFrag + ((size_t)(tt) * 64 + lane) * 8);
        bf16x8 bz_ = *(const bf16x8*)(wFrag + ((size_t)(8 + tt) * 64 + lane) * 8);
        bf16x8 bn_ = *(const bf16x8*)(wFrag + ((size_t)(16 + tt) * 64 + lane) * 8);
        acc_r[0][t] = mfma_bf16(x0, br_, acc_r[0][t]);
        acc_r[1][t] = mfma_bf16(x1, br_, acc_r[1][t]);
        acc_z[0][t] = mfma_bf16(x0, bz_, acc_z[0][t]);
        acc_z[1][t] = mfma_bf16(x1, bz_, acc_z[1][t]);
        acc_in[0][t] = mfma_bf16(x0, bn_, acc_in[0][t]);
        acc_in[1][t] = mfma_bf16(x1, bn_, acc_in[1][t]);
    }
    #pragma unroll 2
    for (int ks = 1; ks <= 8; ++ks) {
        bf16x8 a0 = *(const bf16x8*)(&h_lds[l15 * LDH + (ks - 1) * 32 + 8 * lg]);
        bf16x8 a1 = *(const bf16x8*)(&h_lds[(16 + l15) * LDH + (ks - 1) * 32 + 8 * lg]);
        size_t fb = (size_t)ks * 24 * 64;
        #pragma unroll
        for (int t = 0; t < 2; ++t) {
            int tt = 2 * w + t;
            bf16x8 br_ = *(const bf16x8*)(wFrag + (fb + (size_t)(tt) * 64 + lane) * 8);
            bf16x8 bz_ = *(const bf16x8*)(wFrag + (fb + (size_t)(8 + tt) * 64 + lane) * 8);
            bf16x8 bn_ = *(const bf16x8*)(wFrag + (fb + (size_t)(16 + tt) * 64 + lane) * 8);
            acc_r[0][t] = mfma_bf16(a0, br_, acc_r[0][t]);
            acc_r[1][t] = mfma_bf16(a1, br_, acc_r[1][t]);
            acc_z[0][t] = mfma_bf16(a0, bz_, acc_z[0][t]);
            acc_z[1][t] = mfma_bf16(a1, bz_, acc_z[1][t]);
            acc_hn[0][t] = mfma_bf16(a0, bn_, acc_hn[0][t]);
            acc_hn[1][t] = mfma_bf16(a1, bn_, acc_hn[1][t]);
        }
    }
    #pragma unroll
    for (int t = 0; t < 2; ++t) {
        int u = w * 32 + t * 16 + l15;
        float br = bias[u], bz = bias[128 + u], bin = bias[256 + u], bhn = bias[384 + u];
        #pragma unroll
        for (int rt = 0; rt < 2; ++rt) {
            float4 mv = *(const float4*)(masks + rx + rt * 16 + lg * 4);
            const float* mp = (const float*)&mv;
            #pragma unroll
            for (int reg = 0; reg < 4; ++reg) {
                int row = rt * 16 + lg * 4 + reg;
                float rg = fast_sigmoid(acc_r[rt][t][reg] + br);
                float zg = fast_sigmoid(acc_z[rt][t][reg] + bz);
                float cg = fast_tanh(acc_in[rt][t][reg] + bin + rg * (acc_hn[rt][t][reg] + bhn));
                float h1 = bf2f(h_lds[row * LDH + u]);
                float h2 = bf2f(h_lds[row * LDH + 128 + u]);
                float ho = (1.f - zg) * cg + zg * 0.5f * (h1 + h2);
                outb[((size_t)n * B + (size_t)q * 32 + row) * H + u] = f2bf(ho * mp[reg]);
            }
        }
    }
}

// ---------------------------------------------------------------------------
// Pair kernel: levels (du, dl=du-1) + optional fused projection at dl==0.
// Grid = (1<<dl)*8: block (p = bid>>3 parent node, c8 = bid&7 16-row chunk).
// Children tile M=32 (nodes 2p,2p+1 x 16 rows) -> epilogue writes straight
// into parent's LDS h-region; parent tile M=16 -> global (+proj).
// ---------------------------------------------------------------------------
__global__ __launch_bounds__(NTHR, 4) void pair_kernel(
    const float* __restrict__ targets, const float* __restrict__ masks,
    int du,
    const unsigned short* __restrict__ prev,    // lvl(du+1)
    unsigned short* __restrict__ outl,          // lvl(dl)
    const unsigned short* __restrict__ wFrag, const float* __restrict__ bias,
    int do_proj, const unsigned short* __restrict__ pFrag, float* __restrict__ proj_out)
{
    __shared__ __attribute__((aligned(16))) unsigned short hc[32 * LDH];  // children h-in
    __shared__ __attribute__((aligned(16))) unsigned short hp[16 * LDH];  // parent h-in

    const int tid = threadIdx.x;
    const int lane = tid & 63;
    const int w = tid >> 6;
    const int l15 = lane & 15;
    const int lg = lane >> 4;
    const int p = blockIdx.x >> 3;
    const int c8 = blockIdx.x & 7;
    const int dl = du - 1;

    // stage grandchildren h: row r<16 = child0 ([4p|4p+1]), r>=16 = child1 ([4p+2|4p+3])
    #pragma unroll
    for (int t = 0; t < 4; ++t) {
        int task = t * NTHR + tid;
        int row = task >> 5;
        int ck = task & 31;
        int gnode = 4 * p + ((row >> 4) << 1) + (ck >> 4);
        int4 v = *(const int4*)(prev + (((size_t)gnode) * B + (size_t)c8 * 16 + (row & 15)) * H + (ck & 15) * 8);
        *(int4*)(&hc[row * LDH + ck * 8]) = v;
    }
    const size_t cbase = (size_t)((1 << du) - 1) + 2 * p;
    bf16x8 xc0 = load_xfrag(targets + ((cbase) * B + (size_t)c8 * 16 + l15) * V + 8 * lg);
    bf16x8 xc1 = load_xfrag(targets + ((cbase + 1) * B + (size_t)c8 * 16 + l15) * V + 8 * lg);
    const size_t pnode = (size_t)((1 << dl) - 1) + p;
    bf16x8 xp = load_xfrag(targets + (pnode * B + (size_t)c8 * 16 + l15) * V + 8 * lg);
    __syncthreads();

    // ---- children M=32 (rt = child index) ----
    {
        f32x4 z4 = {0.f, 0.f, 0.f, 0.f};
        f32x4 acc_r[2][2], acc_z[2][2], acc_in[2][2], acc_hn[2][2];
        #pragma unroll
        for (int rt = 0; rt < 2; ++rt)
            #pragma unroll
            for (int t = 0; t < 2; ++t) {
                acc_r[rt][t] = z4; acc_z[rt][t] = z4; acc_in[rt][t] = z4; acc_hn[rt][t] = z4;
            }
        #pragma unroll
        for (int t = 0; t < 2; ++t) {
            int tt = 2 * w + t;
            bf16x8 br_ = *(const bf16x8*)(wFrag + ((size_t)(tt) * 64 + lane) * 8);
            bf16x8 bz_ = *(const bf16x8*)(wFrag + ((size_t)(8 + tt) * 64 + lane) * 8);
            bf16x8 bn_ = *(const bf16x8*)(wFrag + ((size_t)(16 + tt) * 64 + lane) * 8);
            acc_r[0][t] = mfma_bf16(xc0, br_, acc_r[0][t]);
            acc_r[1][t] = mfma_bf16(xc1, br_, acc_r[1][t]);
            acc_z[0][t] = mfma_bf16(xc0, bz_, acc_z[0][t]);
            acc_z[1][t] = mfma_bf16(xc1, bz_, acc_z[1][t]);
            acc_in[0][t] = mfma_bf16(xc0, bn_, acc_in[0][t]);
            acc_in[1][t] = mfma_bf16(xc1, bn_, acc_in[1][t]);
        }
        #pragma unroll 2
        for (int ks = 1; ks <= 8; ++ks) {
            bf16x8 a0 = *(const bf16x8*)(&hc[l15 * LDH + (ks - 1) * 32 + 8 * lg]);
            bf16x8 a1 = *(const bf16x8*)(&hc[(16 + l15) * LDH + (ks - 1) * 32 + 8 * lg]);
            size_t fb = (size_t)ks * 24 * 64;
            #pragma unroll
            for (int t = 0; t < 2; ++t) {
                int tt = 2 * w + t;
                bf16x8 br_ = *(const bf16x8*)(wFrag + (fb + (size_t)(tt) * 64 + lane) * 8);
                bf16x8 bz_ = *(const bf16x8*)(wFrag + (fb + (size_t)(8 + tt) * 64 + lane) * 8);
                bf16x8 bn_ = *(const bf16x8*)(wFrag + (fb + (size_t)(16 + tt) * 64 + lane) * 8);
                acc_r[0][t] = mfma_bf16(a0, br_, acc_r[0][t]);
                acc_r[1][t] = mfma_bf16(a1, br_, acc_r[1][t]);
                acc_z[0][t] = mfma_bf16(a0, bz_, acc_z[0][t]);
                acc_z[1][t] = mfma_bf16(a1, bz_, acc_z[1][t]);
                acc_hn[0][t] = mfma_bf16(a0, bn_, acc_hn[0][t]);
                acc_hn[1][t] = mfma_bf16(a1, bn_, acc_hn[1][t]);
            }
        }
        #pragma unroll
        for (int t = 0; t < 2; ++t) {
            int u = w * 32 + t * 16 + l15;
            float br = bias[u], bz = bias[128 + u], bin = bias[256 + u], bhn = bias[384 + u];
            #pragma unroll
            for (int rt = 0; rt < 2; ++rt) {
                float4 mv = *(const float4*)(masks + (cbase + rt) * B + (size_t)c8 * 16 + lg * 4);
                const float* mp = (const float*)&mv;
                #pragma unroll
                for (int reg = 0; reg < 4; ++reg) {
                    int rowl = lg * 4 + reg;            // parent row 0..15
                    int row = rt * 16 + rowl;
                    float rg = fast_sigmoid(acc_r[rt][t][reg] + br);
                    float zg = fast_sigmoid(acc_z[rt][t][reg] + bz);
                    float cg = fast_tanh(acc_in[rt][t][reg] + bin + rg * (acc_hn[rt][t][reg] + bhn));
                    float h1 = bf2f(hc[row * LDH + u]);
                    float h2 = bf2f(hc[row * LDH + 128 + u]);
                    float ho = (1.f - zg) * cg + zg * 0.5f * (h1 + h2);
                    hp[rowl * LDH + rt * 128 + u] = f2bf(ho * mp[reg]);
                }
            }
        }
    }
    __syncthreads();

    // ---- parent M=16 ----
    {
        f32x4 z4 = {0.f, 0.f, 0.f, 0.f};
        f32x4 acc_r[2], acc_z[2], acc_in[2], acc_hn[2];
        #pragma unroll
        for (int t = 0; t < 2; ++t) { acc_r[t] = z4; acc_z[t] = z4; acc_in[t] = z4; acc_hn[t] = z4; }
        #pragma unroll
        for (int t = 0; t < 2; ++t) {
            int tt = 2 * w + t;
            bf16x8 br_ = *(const bf16x8*)(wFrag + ((size_t)(tt) * 64 + lane) * 8);
            bf16x8 bz_ = *(const bf16x8*)(wFrag + ((size_t)(8 + tt) * 64 + lane) * 8);
            bf16x8 bn_ = *(const bf16x8*)(wFrag + ((size_t)(16 + tt) * 64 + lane) * 8);
            acc_r[t] = mfma_bf16(xp, br_, acc_r[t]);
            acc_z[t] = mfma_bf16(xp, bz_, acc_z[t]);
            acc_in[t] = mfma_bf16(xp, bn_, acc_in[t]);
        }
        #pragma unroll 2
        for (int ks = 1; ks <= 8; ++ks) {
            bf16x8 a = *(const bf16x8*)(&hp[l15 * LDH + (ks - 1) * 32 + 8 * lg]);
            size_t fb = (size_t)ks * 24 * 64;
            #pragma unroll
            for (int t = 0; t < 2; ++t) {
                int tt = 2 * w + t;
                bf16x8 br_ = *(const bf16x8*)(wFrag + (fb + (size_t)(tt) * 64 + lane) * 8);
                bf16x8 bz_ = *(const bf16x8*)(wFrag + (fb + (size_t)(8 + tt) * 64 + lane) * 8);
                bf16x8 bn_ = *(const bf16x8*)(wFrag + (fb + (size_t)(16 + tt) * 64 + lane) * 8);
                acc_r[t] = mfma_bf16(a, br_, acc_r[t]);
                acc_z[t] = mfma_bf16(a, bz_, acc_z[t]);
                acc_hn[t] = mfma_bf16(a, bn_, acc_hn[t]);
            }
        }
        #pragma unroll
        for (int t = 0; t < 2; ++t) {
            int u = w * 32 + t * 16 + l15;
            float br = bias[u], bz = bias[128 + u], bin = bias[256 + u], bhn = bias[384 + u];
            float4 mv = *(const float4*)(masks + pnode * B + (size_t)c8 * 16 + lg * 4);
            const float* mp = (const float*)&mv;
            #pragma unroll
            for (int reg = 0; reg < 4; ++reg) {
                int rowl = lg * 4 + reg;
                float rg = fast_sigmoid(acc_r[t][reg] + br);
                float zg = fast_sigmoid(acc_z[t][reg] + bz);
                float cg = fast_tanh(acc_in[t][reg] + bin + rg * (acc_hn[t][reg] + bhn));
                float h1 = bf2f(hp[rowl * LDH + u]);
                float h2 = bf2f(hp[rowl * LDH + 128 + u]);
                float ho = (1.f - zg) * cg + zg * 0.5f * (h1 + h2);
                unsigned short hb = f2bf(ho * mp[reg]);
                outl[((size_t)p * B + (size_t)c8 * 16 + rowl) * H + u] = hb;
                if (do_proj) hp[rowl * LDH + u] = hb;   // safe: only cols<128, own element
            }
        }
    }

    if (do_proj) {
        __syncthreads();
        f32x4 z4 = {0.f, 0.f, 0.f, 0.f};
        f32x4 pa[4] = {z4, z4, z4, z4};
        #pragma unroll
        for (int ks = 0; ks < 4; ++ks) {
            bf16x8 a = *(const bf16x8*)(&hp[l15 * LDH + ks * 32 + 8 * lg]);
            #pragma unroll
            for (int jj = 0; jj < 4; ++jj) {
                bf16x8 f = *(const bf16x8*)(pFrag + (((size_t)ks * 16 + 4 * w + jj) * 64 + lane) * 8);
                pa[jj] = mfma_bf16(a, f, pa[jj]);
            }
        }
        #pragma unroll
        for (int jj = 0; jj < 4; ++jj) {
            int ct2 = 4 * w + jj;
            int sel = ct2 >> 3, tl = ct2 & 7;
            int u = tl * 16 + l15;
            float bb = bias[512 + sel * 128 + u];
            #pragma unroll
            for (int reg = 0; reg < 4; ++reg) {
                int row = c8 * 16 + lg * 4 + reg;
                proj_out[((size_t)sel * B + row) * H + u] = pa[jj][reg] + bb;
            }
        }
    }
}

// ---------------------------------------------------------------------------
extern "C" void kernel_launch(void* const* d_in, const int* in_sizes, int n_in,
                              void* d_out, int out_size, void* d_ws, size_t ws_size,
                              hipStream_t stream)
{
    const float* targets = (const float*)d_in[0];
    const float* masks   = (const float*)d_in[1];
    const float* wir_w = (const float*)d_in[2];  const float* wir_b = (const float*)d_in[3];
    const float* whr_w = (const float*)d_in[4];  const float* whr_b = (const float*)d_in[5];
    const float* wiz_w = (const float*)d_in[6];  const float* wiz_b = (const float*)d_in[7];
    const float* whz_w = (const float*)d_in[8];  const float* whz_b = (const float*)d_in[9];
    const float* win_w = (const float*)d_in[10]; const float* win_b = (const float*)d_in[11];
    const float* whn_w = (const float*)d_in[12]; const float* whn_b = (const float*)d_in[13];
    const float* mu_w  = (const float*)d_in[14]; const float* mu_b  = (const float*)d_in[15];
    const float* lv_w  = (const float*)d_in[16]; const float* lv_b  = (const float*)d_in[17];

    // level buffers (bf16): only 9,8,6,4,2,0 materialize
    unsigned short* ws16 = (unsigned short*)d_ws;
    unsigned short* lvl9 = ws16;                               // 512*128*128
    unsigned short* lvl8 = lvl9 + (size_t)512 * B * H;         // 256*128*128
    unsigned short* lvl6 = lvl8 + (size_t)256 * B * H;         // 64*128*128
    unsigned short* lvl4 = lvl6 + (size_t)64 * B * H;          // 16*128*128
    unsigned short* lvl2 = lvl4 + (size_t)16 * B * H;          // 4*128*128
    unsigned short* lvl0 = lvl2 + (size_t)4 * B * H;           // 1*128*128
    unsigned short* wFrag = lvl0 + (size_t)1 * B * H;          // 110592 bf16
    unsigned short* pFrag = wFrag + 110592;                    // 32768 bf16
    float*          biasw = (float*)(pFrag + 32768);           // 768 fp32

    prep_pack<<<70, 256, 0, stream>>>(
        wir_w, whr_w, wiz_w, whz_w, win_w, whn_w,
        wir_b, whr_b, wiz_b, whz_b, win_b, whn_b,
        mu_w, mu_b, lv_w, lv_b, wFrag, pFrag, biasw);

    leaf_d9_kernel<<<2048, NTHR, 0, stream>>>(targets, masks, lvl9, wFrag, biasw);

    level_kernel<<<1024, NTHR, 0, stream>>>(targets, masks, 255, lvl9, lvl8, wFrag, biasw);

    pair_kernel<<<512, NTHR, 0, stream>>>(targets, masks, 7, lvl8, lvl6, wFrag, biasw,
                                          0, nullptr, nullptr);
    pair_kernel<<<128, NTHR, 0, stream>>>(targets, masks, 5, lvl6, lvl4, wFrag, biasw,
                                          0, nullptr, nullptr);
    pair_kernel<<<32, NTHR, 0, stream>>>(targets, masks, 3, lvl4, lvl2, wFrag, biasw,
                                         0, nullptr, nullptr);
    pair_kernel<<<8, NTHR, 0, stream>>>(targets, masks, 1, lvl2, lvl0, wFrag, biasw,
                                        1, pFrag, (float*)d_out);
}